// Round 6
// baseline (28337.817 us; speedup 1.0000x reference)
//
#include <hip/hip_runtime.h>
#include <math.h>

#define DEV __device__ __forceinline__

// NUMERICS FREEZE: every output element keeps round-1's exact fp order:
// one thread per output, fmaf ascending over k, bias added once at the end.
// Only order-preserving optimizations (tiling/occupancy/fusion) allowed.
// Round-2 lesson: any reorder flips a u < p*zp threshold somewhere -> FAIL.
// Round-6 lesson: 8x8 micro pins total waves at 1024 = 1 wave/SIMD; no
// source-level scheduling fixes that (single-wave wg regressed 112->160us).
// Round-7 lesson: 8x4 micro @ 2 waves/SIMD lands exactly on the LDS-pipe
// floor (2640 ds_read_b128/thread x 12cyc ~= 105us ~= measured 107us).
// This round: B operand moves LDS->register-prefetch-from-L2 (-33% ds_read).

constexpr int NB    = 4096;
constexpr int TT    = 16;
constexpr int KREL  = 720;   // [enc 100 | zwr 3 | zw_prev 3 | zwt_l 50 | zwt_prev 50 | hid 256 | h 256 | pad 2]
constexpr int KTEM  = 880;   // [enc 100 | zw_prev 3 | hid 256 | h 256 | h(whh) 256 | pad 9]
constexpr int KMT   = 576;   // [zwt_l 50 | h_rela 256 | h_temp 256 | pad 14]
constexpr int KGE2  = 208;   // 200 padded
constexpr int NG    = 1024;
constexpr int CH    = 16384; // enc chunk units

constexpr long OUT_ZWHAT   = 0L;
constexpr long OUT_ZWHERE  = 3276800L;
constexpr long OUT_ZPRES   = 3473408L;
constexpr long OUT_KLWHAT  = 3538944L;
constexpr long OUT_HTEMP   = 3547136L;

DEV float sigm(float x)  { return 1.f / (1.f + expf(-x)); }
DEV float softp(float x) { return fmaxf(x, 0.f) + log1pf(expf(-fabsf(x))); }

// ---------------------------------------------------------------- prep ----
// W_relT/W_temT are k-major (transposed): W*T[k][n], n contiguous.
__global__ void prep_kernel(
    const float* __restrict__ wih_rel, const float* __restrict__ whh_rel,
    const float* __restrict__ bih_rel, const float* __restrict__ bhh_rel,
    const float* __restrict__ wih_tem, const float* __restrict__ whh_tem,
    const float* __restrict__ bih_tem, const float* __restrict__ bhh_tem,
    const float* __restrict__ w_lwhat, const float* __restrict__ w_ge2,
    float* __restrict__ W_relT, float* __restrict__ W_temT, float* __restrict__ W_mt,
    float* __restrict__ W_ge2p,
    float* __restrict__ bias_rel, float* __restrict__ bias_tem,
    float* __restrict__ h_rela, float* __restrict__ c_rela,
    float* __restrict__ x_rel, float* __restrict__ x_tem, float* __restrict__ x_mt,
    float* __restrict__ h1_buf, float* __restrict__ out_kl)
{
  long idx = (long)blockIdx.x * 256 + threadIdx.x;
  if (idx < 737280) { int k = (int)(idx >> 10), j = (int)(idx & 1023);
    W_relT[idx] = (k < 462) ? wih_rel[j*462+k] : (k < 718 ? whh_rel[j*256 + (k-462)] : 0.f); return; }
  idx -= 737280;
  if (idx < 901120) { int k = (int)(idx >> 10), j = (int)(idx & 1023);
    W_temT[idx] = (k < 615) ? wih_tem[j*615+k] : (k < 871 ? whh_tem[j*256 + (k-615)] : 0.f); return; }
  idx -= 901120;
  if (idx < 57600) { int j = (int)(idx/576), k = (int)(idx - (long)j*576);
    W_mt[idx] = (k < 562) ? w_lwhat[j*562+k] : 0.f; return; }
  idx -= 57600;
  if (idx < 20800) { int j = (int)(idx/208), k = (int)(idx - (long)j*208);
    W_ge2p[idx] = (k < 200) ? w_ge2[j*200+k] : 0.f; return; }
  idx -= 20800;
  if (idx < 1024) { bias_rel[idx] = bih_rel[idx] + bhh_rel[idx]; return; }
  idx -= 1024;
  if (idx < 1024) { bias_tem[idx] = bih_tem[idx] + bhh_tem[idx]; return; }
  idx -= 1024;
  if (idx < 1048576) { h_rela[idx] = 0.f; return; }
  idx -= 1048576;
  if (idx < 1048576) { c_rela[idx] = 0.f; return; }
  idx -= 1048576;
  if (idx < 2949120) { x_rel[idx] = 0.f; return; }
  idx -= 2949120;
  if (idx < 3604480) { x_tem[idx] = 0.f; return; }
  idx -= 3604480;
  if (idx < 2359296) { x_mt[idx] = 0.f; return; }
  idx -= 2359296;
  if (idx < 3407872) { h1_buf[idx] = 0.f; return; }
  idx -= 3407872;
  if (idx < 8192) { out_kl[idx] = 0.f; return; }
}

// z_where_bias for all 65536 units (round-1 reduction order)
__global__ __launch_bounds__(256) void zwb_kernel(
    const float* __restrict__ hid_all, const float* __restrict__ zwr_all,
    const float* __restrict__ w_pro, const float* __restrict__ b_pro,
    float* __restrict__ zwb_all)
{
  int tid = threadIdx.x;
  long unit0 = (long)blockIdx.x * 16;
  int u = tid >> 4, l = tid & 15;
  const float* hid = hid_all + (unit0 + u) * 256;
  float p0 = 0.f, p1 = 0.f, p2 = 0.f;
  for (int k = l; k < 256; k += 16) {
    float h = hid[k];
    p0 = fmaf(h, w_pro[k],       p0);
    p1 = fmaf(h, w_pro[256 + k], p1);
    p2 = fmaf(h, w_pro[512 + k], p2);
  }
  #pragma unroll
  for (int off = 8; off; off >>= 1) {
    p0 += __shfl_down(p0, off, 16);
    p1 += __shfl_down(p1, off, 16);
    p2 += __shfl_down(p2, off, 16);
  }
  if (l == 0) {
    long unit = unit0 + u;
    zwb_all[unit*3+0] = fmaxf(p0 + b_pro[0], 0.f) + zwr_all[unit*3+0];
    zwb_all[unit*3+1] = fmaxf(p1 + b_pro[1], 0.f) + zwr_all[unit*3+1];
    zwb_all[unit*3+2] = fmaxf(p2 + b_pro[2], 0.f) + zwr_all[unit*3+2];
  }
}

// ------------------------------------------------------------- glimpse ----
DEV float bilin_sample(const float* im, int y, int x) {
  bool valid = ((unsigned)x < 50u) && ((unsigned)y < 50u);
  int yc = min(max(y, 0), 49), xc = min(max(x, 0), 49);
  float v = im[yc*50 + xc];
  return valid ? v : 0.f;
}

__global__ __launch_bounds__(256) void gfill_kernel(
    const float* __restrict__ img, const float* __restrict__ zwbp, int zstride,
    long ibase, int shift, float* __restrict__ g_out)
{
  __shared__ float zwb[16][3];
  int tid = threadIdx.x;
  long unit0 = (long)blockIdx.x * 16;
  if (tid < 48) {
    int u = tid / 3, j = tid - u*3;
    zwb[u][j] = zwbp[(unit0 + u)*(long)zstride + j];
  }
  __syncthreads();
  for (int p = tid; p < 16*400; p += 256) {
    int u = p / 400, pix = p - u*400;
    long item = (ibase + unit0 + u) >> shift;
    float s = zwb[u][0], tx = zwb[u][1], ty = zwb[u][2];
    int iyi = pix / 20, ixi = pix - iyi*20;
    float bx = (2.f*ixi + 1.f)/20.f - 1.f;
    float by = (2.f*iyi + 1.f)/20.f - 1.f;
    float x = s*bx + tx, y = s*by + ty;
    float ix = ((x + 1.f)*50.f - 1.f)*0.5f;
    float iy = ((y + 1.f)*50.f - 1.f)*0.5f;
    float x0f = floorf(ix), y0f = floorf(iy);
    float wx = ix - x0f, wy = iy - y0f;
    int x0 = (int)x0f, y0 = (int)y0f;
    const float* im = img + item*2500;
    float v00 = bilin_sample(im, y0,   x0  );
    float v01 = bilin_sample(im, y0,   x0+1);
    float v10 = bilin_sample(im, y0+1, x0  );
    float v11 = bilin_sample(im, y0+1, x0+1);
    g_out[(unit0+u)*400 + pix] = v00*(1.f-wx)*(1.f-wy) + v01*wx*(1.f-wy)
                               + v10*(1.f-wx)*wy       + v11*wx*wy;
  }
}

// --------------------------------------------------------------- GEMMs ----
// Big-gate GEMM, round-8: 128x64 tile, 256 threads, 8x4 micro, 2 wgs/CU.
// Round-7 showed dur == LDS-pipe floor (2640 ds_read_b128/thread). B operand
// now bypasses LDS: each thread register-prefetches its own W[k][tn..tn+3]
// float4 from global (L2-resident, 16 unique lines/wave/k), overwriting pb[k]
// right after its k-iter -> single 64-VGPR buffer, loads pipeline across the
// 16-k tile. ds_read count drops 2640 -> 1760/thread (A only): LDS floor
// ~70us. fma floor 47us. VMEM pipe takes B (idle today).
// Per-output order unchanged: fmaf ascending k, bias last (bit-identical).
// Thread owns rows {tm+0..3, tm+64..67} x cols {tn+0..3}.
__global__ __launch_bounds__(256, 2) void gemmG_kernel(
    const float* __restrict__ A, int lda,
    const float* __restrict__ Wt, int ldwt,
    const float* __restrict__ bias,
    float* __restrict__ C, int ldc, int K)
{
  __shared__ float As[2][16][132];
  int tid = threadIdx.x;
  int m0 = blockIdx.x << 7, n0 = blockIdx.y << 6;
  // A staging: thread -> row m0+ar, k-cols ak..ak+7 (2-way write alias, free)
  int ar = tid >> 1, ak = (tid & 1) << 3;
  const float* Ap = A + (long)(m0 + ar)*lda + ak;
  // compute fragment offsets
  int tm = (tid & 15) << 2;          // 0,4,...,60  (row group; +0 / +64)
  int tn = ((tid >> 4) & 15) << 2;   // 0,4,...,60  (col group)
  const float* Bp = Wt + n0 + tn;    // this thread's B column group (k-major)
  float acc[8][4] = {};
  float4 pb[16];

  // prologue: A tile 0 -> LDS buf 0; B k=0..15 -> regs
  float4 a0 = *(const float4*)(Ap);
  float4 a1 = *(const float4*)(Ap + 4);
  #pragma unroll
  for (int k = 0; k < 16; k++) pb[k] = *(const float4*)(Bp + (long)k*ldwt);
  As[0][ak+0][ar] = a0.x; As[0][ak+1][ar] = a0.y;
  As[0][ak+2][ar] = a0.z; As[0][ak+3][ar] = a0.w;
  As[0][ak+4][ar] = a1.x; As[0][ak+5][ar] = a1.y;
  As[0][ak+6][ar] = a1.z; As[0][ak+7][ar] = a1.w;
  __syncthreads();
  int buf = 0;
  for (int k0 = 16;; k0 += 16) {
    bool more = k0 < K;
    if (more) {
      a0 = *(const float4*)(Ap + k0);
      a1 = *(const float4*)(Ap + k0 + 4);
    }
    #pragma unroll
    for (int k = 0; k < 16; k++) {
      float4 av0 = *(const float4*)&As[buf][k][tm];
      float4 av1 = *(const float4*)&As[buf][k][tm+64];
      float4 bv  = pb[k];
      float a[8] = {av0.x,av0.y,av0.z,av0.w,av1.x,av1.y,av1.z,av1.w};
      float b[4] = {bv.x,bv.y,bv.z,bv.w};
      #pragma unroll
      for (int i = 0; i < 8; i++)
        #pragma unroll
        for (int j = 0; j < 4; j++)
          acc[i][j] = fmaf(a[i], b[j], acc[i][j]);
      if (more) pb[k] = *(const float4*)(Bp + (long)(k0 + k)*ldwt);
    }
    if (!more) break;
    buf ^= 1;
    As[buf][ak+0][ar] = a0.x; As[buf][ak+1][ar] = a0.y;
    As[buf][ak+2][ar] = a0.z; As[buf][ak+3][ar] = a0.w;
    As[buf][ak+4][ar] = a1.x; As[buf][ak+5][ar] = a1.y;
    As[buf][ak+6][ar] = a1.z; As[buf][ak+7][ar] = a1.w;
    __syncthreads();
  }
  float bj[4];
  #pragma unroll
  for (int j = 0; j < 4; j++) bj[j] = bias[n0 + tn + j];
  #pragma unroll
  for (int i = 0; i < 8; i++) {
    int mi = m0 + tm + (i & 3) + ((i >> 2) << 6);
    float* Crow = C + (long)mi*ldc + n0;
    float4 v = make_float4(acc[i][0]+bj[0], acc[i][1]+bj[1],
                           acc[i][2]+bj[2], acc[i][3]+bj[3]);
    *(float4*)(Crow + tn) = v;
  }
}

// 64x64 tile, 4x4 micro, N-bounded, optional ReLU. K % 16 == 0 REQUIRED.
template<bool RELU>
__global__ __launch_bounds__(256) void gemmNK64_kernel(
    const float* __restrict__ A, int lda,
    const float* __restrict__ W, int ldw,
    const float* __restrict__ bias,
    float* __restrict__ C, int ldc, int K, int N)
{
  __shared__ float As[16][68];
  __shared__ float Bs[16][68];
  int tid = threadIdx.x;
  int m0 = blockIdx.x << 6, n0 = blockIdx.y << 6;
  int r  = tid >> 2;
  int kq = (tid & 3) << 2;
  const float* Ap = A + (long)(m0 + r)*lda + kq;
  const float* Wp = W + (long)(n0 + r)*ldw + kq;
  bool wv = (n0 + r) < N;
  int tm = (tid & 15) << 2;
  int tn = ((tid >> 4) & 15) << 2;
  float acc[4][4] = {};
  float4 a0 = *(const float4*)Ap;
  float4 b0 = wv ? *(const float4*)Wp : make_float4(0.f,0.f,0.f,0.f);
  for (int k0 = 16;; k0 += 16) {
    __syncthreads();
    As[kq+0][r]=a0.x; As[kq+1][r]=a0.y; As[kq+2][r]=a0.z; As[kq+3][r]=a0.w;
    Bs[kq+0][r]=b0.x; Bs[kq+1][r]=b0.y; Bs[kq+2][r]=b0.z; Bs[kq+3][r]=b0.w;
    __syncthreads();
    if (k0 < K) {
      a0 = *(const float4*)(Ap + k0);
      b0 = wv ? *(const float4*)(Wp + k0) : make_float4(0.f,0.f,0.f,0.f);
    }
    #pragma unroll
    for (int k = 0; k < 16; k++) {
      float4 av = *(const float4*)&As[k][tm];
      float4 bv = *(const float4*)&Bs[k][tn];
      float a[4] = {av.x,av.y,av.z,av.w};
      float b[4] = {bv.x,bv.y,bv.z,bv.w};
      #pragma unroll
      for (int i = 0; i < 4; i++)
        #pragma unroll
        for (int j = 0; j < 4; j++)
          acc[i][j] = fmaf(a[i], b[j], acc[i][j]);
    }
    if (k0 >= K) break;
  }
  #pragma unroll
  for (int i = 0; i < 4; i++) {
    int mi = m0 + tm + i;
    float* Crow = C + (long)mi*ldc + n0;
    #pragma unroll
    for (int j = 0; j < 4; j++) {
      int nj = tn + j;
      if (n0 + nj < N) {
        float v = acc[i][j] + bias[n0 + nj];
        if (RELU) v = fmaxf(v, 0.f);
        Crow[nj] = v;
      }
    }
  }
}

// ------------------------------------------------------------ assemble ----
__global__ void assemble_kernel(
    const float* __restrict__ enc_all, const float* __restrict__ zwhat_lt,
    const float* __restrict__ zwhere_lt, const float* __restrict__ hid_lt, int t,
    float* __restrict__ x_rel, float* __restrict__ x_tem, float* __restrict__ x_mt)
{
  long idx = (long)blockIdx.x * 256 + threadIdx.x;
  const int PER = 715;
  long item = idx / PER;
  int c = (int)(idx - item*PER);
  if (item >= NB) return;
  long ut = item*16 + t;
  if (c < 100)      x_rel[item*KREL + c]             = enc_all[ut*100 + c];
  else if (c < 103) x_rel[item*KREL + 100 + (c-100)] = zwhere_lt[ut*3 + (c-100)];
  else if (c < 153) x_rel[item*KREL + 106 + (c-103)] = zwhat_lt[ut*50 + (c-103)];
  else if (c < 409) x_rel[item*KREL + 206 + (c-153)] = hid_lt[ut*256 + (c-153)];
  else if (c < 665) x_tem[item*KTEM + 103 + (c-409)] = hid_lt[ut*256 + (c-409)];
  else              x_mt [item*KMT  + (c-665)]       = zwhat_lt[ut*50 + (c-665)];
}

// ----------------------------------------------------------- pointwise ----
// rel LSTM + m_where/s_where/z_where_i (serial chains, round-3 order)
__global__ __launch_bounds__(256) void lstm_rel_kernel(
    const float* __restrict__ gates,
    float* __restrict__ h_rela, float* __restrict__ c_rela,
    float* __restrict__ x_rel, float* __restrict__ x_tem, float* __restrict__ x_mt,
    const float* __restrict__ zwhere_lt, const float* __restrict__ w_lwhere,
    const float* __restrict__ b_lwhere, const float* __restrict__ eps_where, int t,
    float* __restrict__ m_where, float* __restrict__ s_where,
    float* __restrict__ o_zwhere)
{
  __shared__ float sh[256];
  long item = blockIdx.x;
  int j = threadIdx.x;
  const float* grow = gates + item*1024;
  float ig = grow[j], fg = grow[256+j], gg = grow[512+j], og = grow[768+j];
  long hi = item*256 + j;
  float c  = c_rela[hi];
  float c2 = sigm(fg)*c + sigm(ig)*tanhf(gg);
  float h2 = sigm(og)*tanhf(c2);
  c_rela[hi] = c2;
  h_rela[hi] = h2;
  sh[j] = h2;
  x_tem[item*KTEM + 359 + j] = h2;
  x_tem[item*KTEM + 615 + j] = h2;
  x_mt [item*KMT  +  50 + j] = h2;
  x_rel[item*KREL + 462 + j] = h2;   // for step t+1
  __syncthreads();
  if (j < 3) {
    long ut = item*16 + t;
    const float* wm  = w_lwhere + j*259;
    const float* wsr = w_lwhere + (j+3)*259;
    float am = b_lwhere[j], as = b_lwhere[j+3];
    #pragma unroll
    for (int k = 0; k < 3; k++) {
      float v = zwhere_lt[ut*3 + k];
      am = fmaf(v, wm[k], am);  as = fmaf(v, wsr[k], as);
    }
    for (int k = 0; k < 256; k++) {
      float v = sh[k];
      am = fmaf(v, wm[3+k], am);  as = fmaf(v, wsr[3+k], as);
    }
    float s = softp(as) + 1e-4f;
    float zw = am + s * eps_where[ut*3 + j];
    m_where[item*3 + j] = am;
    s_where[item*3 + j] = s;
    o_zwhere[ut*3 + j]  = zw;
    x_rel[item*KREL + 103 + j] = zw;   // zw_prev for step t+1
  }
}

__global__ void lstm_tem_kernel(const float* __restrict__ gates,
    const float* __restrict__ c_rela, float* __restrict__ o_htemp, int t,
    float* __restrict__ x_mt, float* __restrict__ x_tem,
    const float* __restrict__ o_zwhere)
{
  long idx = (long)blockIdx.x * 256 + threadIdx.x;
  if (idx >= (long)NB*256) return;
  long item = idx >> 8; int j = (int)(idx & 255);
  const float* grow = gates + item*1024;
  float ig = grow[j], fg = grow[256+j], gg = grow[512+j], og = grow[768+j];
  float c  = c_rela[idx];
  float c2 = sigm(fg)*c + sigm(ig)*tanhf(gg);
  float h2 = sigm(og)*tanhf(c2);
  long ut = item*16 + t;
  o_htemp[ut*256 + j] = h2;
  x_mt[item*KMT + 306 + j] = h2;
  if (j < 3) x_tem[item*KTEM + 100 + j] = o_zwhere[ut*3 + j];  // zw_prev for t+1
}

// pres + z_what sampling fused (z_what values identical to round-3 zwhat_kernel)
__global__ __launch_bounds__(256) void pres_kernel(
    const float* __restrict__ o_zwhere,
    const float* __restrict__ h_rela, const float* __restrict__ o_htemp,
    const float* __restrict__ w_lpres, const float* __restrict__ b_lpres,
    const float* __restrict__ zpres_lt, const float* __restrict__ u_pres, int t,
    const float* __restrict__ mt, const float* __restrict__ m_where,
    const float* __restrict__ s_where, const float* __restrict__ eps_what,
    float* __restrict__ o_zwhat, float* __restrict__ x_rel,
    float* __restrict__ o_zpres, float* __restrict__ out_klwhat,
    float* __restrict__ out_klwhere)
{
  int tid = threadIdx.x;
  long item = (long)blockIdx.x*4 + (tid >> 6);
  if (item >= NB) return;
  int l = tid & 63;
  long ut = item*16 + t;
  float part = 0.f;
  for (int c = l; c < 565; c += 64) {
    float x;
    if (c < 50) {
      float m = mt[item*100 + c];
      float s = softp(mt[item*100 + 50 + c]) + 1e-4f;
      x = m + s * eps_what[ut*50 + c];
      o_zwhat[ut*50 + c] = x;
      x_rel[item*KREL + 156 + c] = x;   // zwt_prev for step t+1
    }
    else if (c < 53)  x = o_zwhere[ut*3 + (c-50)];
    else if (c < 309) x = h_rela[item*256 + (c-53)];
    else              x = o_htemp[ut*256 + (c-309)];
    part = fmaf(x, w_lpres[c], part);
  }
  #pragma unroll
  for (int off = 32; off; off >>= 1) part += __shfl_down(part, off);
  float zpres = 0.f;
  if (l == 0) {
    float p = sigm(part + b_lpres[0]);
    zpres = (u_pres[ut] < p * zpres_lt[ut]) ? 1.f : 0.f;
    o_zpres[ut] = zpres;
  }
  float w = __shfl(zpres, 0);
  float kw = 0.f, kwh = 0.f;
  if (l < 50) {
    float m = mt[item*100 + l];
    float s = softp(mt[item*100 + 50 + l]) + 1e-4f;
    kw = -logf(s) + 0.5f*(s*s + m*m) - 0.5f;
  }
  if (l < 3) {
    float m = m_where[item*3 + l], s = s_where[item*3 + l];
    float m0 = (l == 0) ? 0.3f : 0.f;
    float s0 = (l == 0) ? 0.1f : 1.f;
    kwh = logf(s0 / s) + (s*s + (m-m0)*(m-m0)) / (2.f*s0*s0) - 0.5f;
  }
  #pragma unroll
  for (int off = 32; off; off >>= 1) {
    kw  += __shfl_down(kw,  off);
    kwh += __shfl_down(kwh, off);
  }
  if (l == 0) {
    out_klwhat[item]  += w * kw;
    out_klwhere[item] += w * kwh;
  }
}

// ---------------------------------------------------------------- host ----
extern "C" void kernel_launch(void* const* d_in, const int* in_sizes, int n_in,
                              void* d_out, int out_size, void* d_ws, size_t ws_size,
                              hipStream_t stream) {
  (void)in_sizes; (void)n_in; (void)out_size; (void)ws_size;
  const float* img       = (const float*)d_in[0];
  const float* zwhat_lt  = (const float*)d_in[1];
  const float* zwhere_lt = (const float*)d_in[2];
  const float* zpres_lt  = (const float*)d_in[3];
  const float* hid_lt    = (const float*)d_in[4];
  const float* eps_where = (const float*)d_in[5];
  const float* eps_what  = (const float*)d_in[6];
  const float* u_pres    = (const float*)d_in[7];
  const float* w_pro     = (const float*)d_in[8];
  const float* b_pro     = (const float*)d_in[9];
  const float* w_ge1     = (const float*)d_in[10];
  const float* b_ge1     = (const float*)d_in[11];
  const float* w_ge2     = (const float*)d_in[12];
  const float* b_ge2     = (const float*)d_in[13];
  const float* wih_rel   = (const float*)d_in[14];
  const float* whh_rel   = (const float*)d_in[15];
  const float* bih_rel   = (const float*)d_in[16];
  const float* bhh_rel   = (const float*)d_in[17];
  const float* wih_tem   = (const float*)d_in[18];
  const float* whh_tem   = (const float*)d_in[19];
  const float* bih_tem   = (const float*)d_in[20];
  const float* bhh_tem   = (const float*)d_in[21];
  const float* w_lwhere  = (const float*)d_in[22];
  const float* b_lwhere  = (const float*)d_in[23];
  const float* w_lwhat   = (const float*)d_in[24];
  const float* b_lwhat   = (const float*)d_in[25];
  const float* w_lpres   = (const float*)d_in[26];
  const float* b_lpres   = (const float*)d_in[27];

  float* ws = (float*)d_ws;
  float* W_relT   = ws;                       // 737280  (720 x 1024, k-major)
  float* W_temT   = W_relT + 737280;          // 901120  (880 x 1024, k-major)
  float* W_mt     = W_temT + 901120;          // 57600
  float* W_ge2p   = W_mt + 57600;             // 20800
  float* bias_rel = W_ge2p + 20800;           // 1024
  float* bias_tem = bias_rel + 1024;          // 1024
  float* zwb_all  = bias_tem + 1024;          // 196608
  float* enc_all  = zwb_all + 196608;         // 6553600
  float* g_buf    = enc_all + 6553600;        // 6553600 (CH*400)
  float* h1_buf   = g_buf + 6553600;          // 3407872 (CH*208)
  float* x_rel    = h1_buf + 3407872;         // 2949120
  float* x_tem    = x_rel + 2949120;          // 3604480
  float* x_mt     = x_tem + 3604480;          // 2359296
  float* gates    = x_mt + 2359296;           // 4194304
  float* h_rela   = gates + 4194304;          // 1048576
  float* c_rela   = h_rela + 1048576;         // 1048576
  float* m_where  = c_rela + 1048576;         // 12288
  float* s_where  = m_where + 12288;          // 12288
  float* mtbuf    = s_where + 12288;          // 409600

  float* out       = (float*)d_out;
  float* o_zwhat   = out + OUT_ZWHAT;
  float* o_zwhere  = out + OUT_ZWHERE;
  float* o_zpres   = out + OUT_ZPRES;
  float* o_klwhat  = out + OUT_KLWHAT;
  float* o_htemp   = out + OUT_HTEMP;

  prep_kernel<<<63067, 256, 0, stream>>>(wih_rel, whh_rel, bih_rel, bhh_rel,
      wih_tem, whh_tem, bih_tem, bhh_tem, w_lwhat, w_ge2,
      W_relT, W_temT, W_mt, W_ge2p, bias_rel, bias_tem, h_rela, c_rela,
      x_rel, x_tem, x_mt, h1_buf, o_klwhat);

  zwb_kernel<<<4096, 256, 0, stream>>>(hid_lt, zwhere_lt, w_pro, b_pro, zwb_all);

  for (int c = 0; c < 4; c++) {
    gfill_kernel<<<CH/16, 256, 0, stream>>>(img, zwb_all + (long)c*CH*3, 3,
        (long)c*CH, 4, g_buf);
    gemmNK64_kernel<true><<<dim3(CH/64, 4), 256, 0, stream>>>(
        g_buf, 400, w_ge1, 400, b_ge1, h1_buf, KGE2, 400, 200);
    gemmNK64_kernel<false><<<dim3(CH/64, 2), 256, 0, stream>>>(
        h1_buf, KGE2, W_ge2p, KGE2, b_ge2, enc_all + (long)c*CH*100, 100, KGE2, 100);
  }

  for (int t = 0; t < TT; t++) {
    assemble_kernel<<<11440, 256, 0, stream>>>(enc_all, zwhat_lt, zwhere_lt,
        hid_lt, t, x_rel, x_tem, x_mt);
    gemmG_kernel<<<dim3(32, 16), 256, 0, stream>>>(x_rel, KREL, W_relT, NG,
        bias_rel, gates, NG, KREL);
    lstm_rel_kernel<<<4096, 256, 0, stream>>>(gates, h_rela, c_rela,
        x_rel, x_tem, x_mt, zwhere_lt, w_lwhere, b_lwhere, eps_where, t,
        m_where, s_where, o_zwhere);
    gfill_kernel<<<256, 256, 0, stream>>>(img, o_zwhere + t*3, 48, 0, 0, g_buf);
    gemmNK64_kernel<true><<<dim3(64, 4), 256, 0, stream>>>(
        g_buf, 400, w_ge1, 400, b_ge1, h1_buf, KGE2, 400, 200);
    gemmNK64_kernel<false><<<dim3(64, 2), 256, 0, stream>>>(
        h1_buf, KGE2, W_ge2p, KGE2, b_ge2, x_tem, KTEM, KGE2, 100);
    gemmG_kernel<<<dim3(32, 16), 256, 0, stream>>>(x_tem, KTEM, W_temT, NG,
        bias_tem, gates, NG, KTEM);
    lstm_tem_kernel<<<4096, 256, 0, stream>>>(gates, c_rela, o_htemp, t,
        x_mt, x_tem, o_zwhere);
    gemmNK64_kernel<false><<<dim3(64, 2), 256, 0, stream>>>(
        x_mt, KMT, W_mt, KMT, b_lwhat, mtbuf, 100, KMT, 100);
    pres_kernel<<<1024, 256, 0, stream>>>(o_zwhere, h_rela, o_htemp,
        w_lpres, b_lpres, zpres_lt, u_pres, t, mtbuf, m_where, s_where,
        eps_what, o_zwhat, x_rel, o_zpres, o_klwhat, o_klwhat + 4096);
  }
}

// Round 7
// 6256.455 us; speedup vs baseline: 4.5294x; 4.5294x over previous
//
#include <hip/hip_runtime.h>
#include <math.h>

#define DEV __device__ __forceinline__

// NUMERICS FREEZE: every output element keeps round-1's exact fp order:
// one thread per output, fmaf ascending over k, bias added once at the end.
// Only order-preserving optimizations (tiling/occupancy/fusion) allowed.
// Round-2 lesson: any reorder flips a u < p*zp threshold somewhere -> FAIL.
// Round-6 lesson: 8x8 micro pins total waves at 1024 = 1 wave/SIMD.
// Round-7 lesson: 8x4 micro @ 2 waves/SIMD == LDS-pipe floor (~107us).
// Round-8 lesson (gemmG): pb[16] float4 = 64 VGPR buffer under the
// __launch_bounds__(256,2) 128-VGPR cap -> scratch spill (WRITE_SIZE 2GB,
// 898us). Register operand buffers must stay tiny.
// This round (gemmR): 4x8 micro, wave-uniform B. A via 1 ds_read_b128/k
// (32B/thread/k, -33% LDS bytes); B via per-tile vB regs + v_readlane
// (VALU, immediate lane) -> B off the LDS pipe, only 4 VGPRs.

constexpr int NB    = 4096;
constexpr int TT    = 16;
constexpr int KREL  = 720;   // [enc 100 | zwr 3 | zw_prev 3 | zwt_l 50 | zwt_prev 50 | hid 256 | h 256 | pad 2]
constexpr int KTEM  = 880;   // [enc 100 | zw_prev 3 | hid 256 | h 256 | h(whh) 256 | pad 9]
constexpr int KMT   = 576;   // [zwt_l 50 | h_rela 256 | h_temp 256 | pad 14]
constexpr int KGE2  = 208;   // 200 padded
constexpr int NG    = 1024;
constexpr int CH    = 16384; // enc chunk units

constexpr long OUT_ZWHAT   = 0L;
constexpr long OUT_ZWHERE  = 3276800L;
constexpr long OUT_ZPRES   = 3473408L;
constexpr long OUT_KLWHAT  = 3538944L;
constexpr long OUT_HTEMP   = 3547136L;

DEV float sigm(float x)  { return 1.f / (1.f + expf(-x)); }
DEV float softp(float x) { return fmaxf(x, 0.f) + log1pf(expf(-fabsf(x))); }
DEV float rdlane(float v, int l) {
  return __int_as_float(__builtin_amdgcn_readlane(__float_as_int(v), l));
}

// ---------------------------------------------------------------- prep ----
// W_relT/W_temT are k-major (transposed): W*T[k][n], n contiguous.
__global__ void prep_kernel(
    const float* __restrict__ wih_rel, const float* __restrict__ whh_rel,
    const float* __restrict__ bih_rel, const float* __restrict__ bhh_rel,
    const float* __restrict__ wih_tem, const float* __restrict__ whh_tem,
    const float* __restrict__ bih_tem, const float* __restrict__ bhh_tem,
    const float* __restrict__ w_lwhat, const float* __restrict__ w_ge2,
    float* __restrict__ W_relT, float* __restrict__ W_temT, float* __restrict__ W_mt,
    float* __restrict__ W_ge2p,
    float* __restrict__ bias_rel, float* __restrict__ bias_tem,
    float* __restrict__ h_rela, float* __restrict__ c_rela,
    float* __restrict__ x_rel, float* __restrict__ x_tem, float* __restrict__ x_mt,
    float* __restrict__ h1_buf, float* __restrict__ out_kl)
{
  long idx = (long)blockIdx.x * 256 + threadIdx.x;
  if (idx < 737280) { int k = (int)(idx >> 10), j = (int)(idx & 1023);
    W_relT[idx] = (k < 462) ? wih_rel[j*462+k] : (k < 718 ? whh_rel[j*256 + (k-462)] : 0.f); return; }
  idx -= 737280;
  if (idx < 901120) { int k = (int)(idx >> 10), j = (int)(idx & 1023);
    W_temT[idx] = (k < 615) ? wih_tem[j*615+k] : (k < 871 ? whh_tem[j*256 + (k-615)] : 0.f); return; }
  idx -= 901120;
  if (idx < 57600) { int j = (int)(idx/576), k = (int)(idx - (long)j*576);
    W_mt[idx] = (k < 562) ? w_lwhat[j*562+k] : 0.f; return; }
  idx -= 57600;
  if (idx < 20800) { int j = (int)(idx/208), k = (int)(idx - (long)j*208);
    W_ge2p[idx] = (k < 200) ? w_ge2[j*200+k] : 0.f; return; }
  idx -= 20800;
  if (idx < 1024) { bias_rel[idx] = bih_rel[idx] + bhh_rel[idx]; return; }
  idx -= 1024;
  if (idx < 1024) { bias_tem[idx] = bih_tem[idx] + bhh_tem[idx]; return; }
  idx -= 1024;
  if (idx < 1048576) { h_rela[idx] = 0.f; return; }
  idx -= 1048576;
  if (idx < 1048576) { c_rela[idx] = 0.f; return; }
  idx -= 1048576;
  if (idx < 2949120) { x_rel[idx] = 0.f; return; }
  idx -= 2949120;
  if (idx < 3604480) { x_tem[idx] = 0.f; return; }
  idx -= 3604480;
  if (idx < 2359296) { x_mt[idx] = 0.f; return; }
  idx -= 2359296;
  if (idx < 3407872) { h1_buf[idx] = 0.f; return; }
  idx -= 3407872;
  if (idx < 8192) { out_kl[idx] = 0.f; return; }
}

// z_where_bias for all 65536 units (round-1 reduction order)
__global__ __launch_bounds__(256) void zwb_kernel(
    const float* __restrict__ hid_all, const float* __restrict__ zwr_all,
    const float* __restrict__ w_pro, const float* __restrict__ b_pro,
    float* __restrict__ zwb_all)
{
  int tid = threadIdx.x;
  long unit0 = (long)blockIdx.x * 16;
  int u = tid >> 4, l = tid & 15;
  const float* hid = hid_all + (unit0 + u) * 256;
  float p0 = 0.f, p1 = 0.f, p2 = 0.f;
  for (int k = l; k < 256; k += 16) {
    float h = hid[k];
    p0 = fmaf(h, w_pro[k],       p0);
    p1 = fmaf(h, w_pro[256 + k], p1);
    p2 = fmaf(h, w_pro[512 + k], p2);
  }
  #pragma unroll
  for (int off = 8; off; off >>= 1) {
    p0 += __shfl_down(p0, off, 16);
    p1 += __shfl_down(p1, off, 16);
    p2 += __shfl_down(p2, off, 16);
  }
  if (l == 0) {
    long unit = unit0 + u;
    zwb_all[unit*3+0] = fmaxf(p0 + b_pro[0], 0.f) + zwr_all[unit*3+0];
    zwb_all[unit*3+1] = fmaxf(p1 + b_pro[1], 0.f) + zwr_all[unit*3+1];
    zwb_all[unit*3+2] = fmaxf(p2 + b_pro[2], 0.f) + zwr_all[unit*3+2];
  }
}

// ------------------------------------------------------------- glimpse ----
DEV float bilin_sample(const float* im, int y, int x) {
  bool valid = ((unsigned)x < 50u) && ((unsigned)y < 50u);
  int yc = min(max(y, 0), 49), xc = min(max(x, 0), 49);
  float v = im[yc*50 + xc];
  return valid ? v : 0.f;
}

__global__ __launch_bounds__(256) void gfill_kernel(
    const float* __restrict__ img, const float* __restrict__ zwbp, int zstride,
    long ibase, int shift, float* __restrict__ g_out)
{
  __shared__ float zwb[16][3];
  int tid = threadIdx.x;
  long unit0 = (long)blockIdx.x * 16;
  if (tid < 48) {
    int u = tid / 3, j = tid - u*3;
    zwb[u][j] = zwbp[(unit0 + u)*(long)zstride + j];
  }
  __syncthreads();
  for (int p = tid; p < 16*400; p += 256) {
    int u = p / 400, pix = p - u*400;
    long item = (ibase + unit0 + u) >> shift;
    float s = zwb[u][0], tx = zwb[u][1], ty = zwb[u][2];
    int iyi = pix / 20, ixi = pix - iyi*20;
    float bx = (2.f*ixi + 1.f)/20.f - 1.f;
    float by = (2.f*iyi + 1.f)/20.f - 1.f;
    float x = s*bx + tx, y = s*by + ty;
    float ix = ((x + 1.f)*50.f - 1.f)*0.5f;
    float iy = ((y + 1.f)*50.f - 1.f)*0.5f;
    float x0f = floorf(ix), y0f = floorf(iy);
    float wx = ix - x0f, wy = iy - y0f;
    int x0 = (int)x0f, y0 = (int)y0f;
    const float* im = img + item*2500;
    float v00 = bilin_sample(im, y0,   x0  );
    float v01 = bilin_sample(im, y0,   x0+1);
    float v10 = bilin_sample(im, y0+1, x0  );
    float v11 = bilin_sample(im, y0+1, x0+1);
    g_out[(unit0+u)*400 + pix] = v00*(1.f-wx)*(1.f-wy) + v01*wx*(1.f-wy)
                               + v10*(1.f-wx)*wy       + v11*wx*wy;
  }
}

// --------------------------------------------------------------- GEMMs ----
// Big-gate GEMM, round-9 "gemmR": 256x32 tile, 256 threads, 4x8 micro,
// 2 wgs/CU (2 waves/SIMD). Wave w owns cols c0=n0+8w (wave-uniform!);
// lane l owns rows m0+4l..+3.
//   A: LDS [k][m] layout, 1 ds_read_b128 per k per lane (consecutive,
//      conflict-free) -> 32B/thread/k (was 48 in round-7).
//   B: NOT in LDS. Per 16-k tile each lane loads 2 scalars from L2-resident
//      W: vb0 = W[k0+(l&15)][c0+(l>>4)], vb1 = +4 cols. Per k, the 8
//      wave-uniform b values come via v_readlane (immediate lane (j<<4)|k,
//      VALU pipe) into the fma's SGPR operand. Only 4 VGPRs of B state
//      (round-8 spill lesson).
// Per-output order unchanged: fmaf ascending k, bias last (bit-identical).
__global__ __launch_bounds__(256, 2) void gemmR_kernel(
    const float* __restrict__ A, int lda,
    const float* __restrict__ Wt, int ldwt,
    const float* __restrict__ bias,
    float* __restrict__ C, int ldc, int K)
{
  __shared__ float As[2][16][256];
  int tid  = threadIdx.x;
  int lane = tid & 63;
  int w    = tid >> 6;
  int m0 = blockIdx.x << 8;           // 256-row tile
  int n0 = blockIdx.y << 5;           // 32-col tile
  int c0 = n0 + (w << 3);             // this wave's 8 columns
  const float* Ap  = A + (long)(m0 + tid)*lda;          // this thread's A row
  const float* BpL = Wt + (long)(lane & 15)*ldwt + c0 + (lane >> 4);
  float acc[4][8] = {};

  // prologue: tile 0
  float4 pa0 = *(const float4*)(Ap + 0);
  float4 pa1 = *(const float4*)(Ap + 4);
  float4 pa2 = *(const float4*)(Ap + 8);
  float4 pa3 = *(const float4*)(Ap + 12);
  float vb0 = BpL[0];
  float vb1 = BpL[4];
  As[0][ 0][tid]=pa0.x; As[0][ 1][tid]=pa0.y; As[0][ 2][tid]=pa0.z; As[0][ 3][tid]=pa0.w;
  As[0][ 4][tid]=pa1.x; As[0][ 5][tid]=pa1.y; As[0][ 6][tid]=pa1.z; As[0][ 7][tid]=pa1.w;
  As[0][ 8][tid]=pa2.x; As[0][ 9][tid]=pa2.y; As[0][10][tid]=pa2.z; As[0][11][tid]=pa2.w;
  As[0][12][tid]=pa3.x; As[0][13][tid]=pa3.y; As[0][14][tid]=pa3.z; As[0][15][tid]=pa3.w;
  __syncthreads();

  int buf = 0;
  for (int k0 = 16;; k0 += 16) {
    bool more = k0 < K;
    float nb0, nb1;
    if (more) {
      pa0 = *(const float4*)(Ap + k0);
      pa1 = *(const float4*)(Ap + k0 + 4);
      pa2 = *(const float4*)(Ap + k0 + 8);
      pa3 = *(const float4*)(Ap + k0 + 12);
      nb0 = BpL[(long)k0*ldwt];
      nb1 = BpL[(long)k0*ldwt + 4];
    }
    #pragma unroll
    for (int k = 0; k < 16; k++) {
      float4 av = *(const float4*)&As[buf][k][lane << 2];
      float a[4] = {av.x, av.y, av.z, av.w};
      #pragma unroll
      for (int j = 0; j < 8; j++) {
        float bb = (j < 4) ? rdlane(vb0, (j << 4) | k)
                           : rdlane(vb1, ((j - 4) << 4) | k);
        #pragma unroll
        for (int i = 0; i < 4; i++)
          acc[i][j] = fmaf(a[i], bb, acc[i][j]);
      }
    }
    if (!more) break;
    buf ^= 1;
    As[buf][ 0][tid]=pa0.x; As[buf][ 1][tid]=pa0.y; As[buf][ 2][tid]=pa0.z; As[buf][ 3][tid]=pa0.w;
    As[buf][ 4][tid]=pa1.x; As[buf][ 5][tid]=pa1.y; As[buf][ 6][tid]=pa1.z; As[buf][ 7][tid]=pa1.w;
    As[buf][ 8][tid]=pa2.x; As[buf][ 9][tid]=pa2.y; As[buf][10][tid]=pa2.z; As[buf][11][tid]=pa2.w;
    As[buf][12][tid]=pa3.x; As[buf][13][tid]=pa3.y; As[buf][14][tid]=pa3.z; As[buf][15][tid]=pa3.w;
    vb0 = nb0; vb1 = nb1;
    __syncthreads();
  }

  float bj[8];
  #pragma unroll
  for (int j = 0; j < 8; j++) bj[j] = bias[c0 + j];
  #pragma unroll
  for (int i = 0; i < 4; i++) {
    int mi = m0 + (lane << 2) + i;
    float* Crow = C + (long)mi*ldc + c0;
    float4 v0 = make_float4(acc[i][0]+bj[0], acc[i][1]+bj[1],
                            acc[i][2]+bj[2], acc[i][3]+bj[3]);
    float4 v1 = make_float4(acc[i][4]+bj[4], acc[i][5]+bj[5],
                            acc[i][6]+bj[6], acc[i][7]+bj[7]);
    *(float4*)(Crow)     = v0;
    *(float4*)(Crow + 4) = v1;
  }
}

// 64x64 tile, 4x4 micro, N-bounded, optional ReLU. K % 16 == 0 REQUIRED.
template<bool RELU>
__global__ __launch_bounds__(256) void gemmNK64_kernel(
    const float* __restrict__ A, int lda,
    const float* __restrict__ W, int ldw,
    const float* __restrict__ bias,
    float* __restrict__ C, int ldc, int K, int N)
{
  __shared__ float As[16][68];
  __shared__ float Bs[16][68];
  int tid = threadIdx.x;
  int m0 = blockIdx.x << 6, n0 = blockIdx.y << 6;
  int r  = tid >> 2;
  int kq = (tid & 3) << 2;
  const float* Ap = A + (long)(m0 + r)*lda + kq;
  const float* Wp = W + (long)(n0 + r)*ldw + kq;
  bool wv = (n0 + r) < N;
  int tm = (tid & 15) << 2;
  int tn = ((tid >> 4) & 15) << 2;
  float acc[4][4] = {};
  float4 a0 = *(const float4*)Ap;
  float4 b0 = wv ? *(const float4*)Wp : make_float4(0.f,0.f,0.f,0.f);
  for (int k0 = 16;; k0 += 16) {
    __syncthreads();
    As[kq+0][r]=a0.x; As[kq+1][r]=a0.y; As[kq+2][r]=a0.z; As[kq+3][r]=a0.w;
    Bs[kq+0][r]=b0.x; Bs[kq+1][r]=b0.y; Bs[kq+2][r]=b0.z; Bs[kq+3][r]=b0.w;
    __syncthreads();
    if (k0 < K) {
      a0 = *(const float4*)(Ap + k0);
      b0 = wv ? *(const float4*)(Wp + k0) : make_float4(0.f,0.f,0.f,0.f);
    }
    #pragma unroll
    for (int k = 0; k < 16; k++) {
      float4 av = *(const float4*)&As[k][tm];
      float4 bv = *(const float4*)&Bs[k][tn];
      float a[4] = {av.x,av.y,av.z,av.w};
      float b[4] = {bv.x,bv.y,bv.z,bv.w};
      #pragma unroll
      for (int i = 0; i < 4; i++)
        #pragma unroll
        for (int j = 0; j < 4; j++)
          acc[i][j] = fmaf(a[i], b[j], acc[i][j]);
    }
    if (k0 >= K) break;
  }
  #pragma unroll
  for (int i = 0; i < 4; i++) {
    int mi = m0 + tm + i;
    float* Crow = C + (long)mi*ldc + n0;
    #pragma unroll
    for (int j = 0; j < 4; j++) {
      int nj = tn + j;
      if (n0 + nj < N) {
        float v = acc[i][j] + bias[n0 + nj];
        if (RELU) v = fmaxf(v, 0.f);
        Crow[nj] = v;
      }
    }
  }
}

// ------------------------------------------------------------ assemble ----
__global__ void assemble_kernel(
    const float* __restrict__ enc_all, const float* __restrict__ zwhat_lt,
    const float* __restrict__ zwhere_lt, const float* __restrict__ hid_lt, int t,
    float* __restrict__ x_rel, float* __restrict__ x_tem, float* __restrict__ x_mt)
{
  long idx = (long)blockIdx.x * 256 + threadIdx.x;
  const int PER = 715;
  long item = idx / PER;
  int c = (int)(idx - item*PER);
  if (item >= NB) return;
  long ut = item*16 + t;
  if (c < 100)      x_rel[item*KREL + c]             = enc_all[ut*100 + c];
  else if (c < 103) x_rel[item*KREL + 100 + (c-100)] = zwhere_lt[ut*3 + (c-100)];
  else if (c < 153) x_rel[item*KREL + 106 + (c-103)] = zwhat_lt[ut*50 + (c-103)];
  else if (c < 409) x_rel[item*KREL + 206 + (c-153)] = hid_lt[ut*256 + (c-153)];
  else if (c < 665) x_tem[item*KTEM + 103 + (c-409)] = hid_lt[ut*256 + (c-409)];
  else              x_mt [item*KMT  + (c-665)]       = zwhat_lt[ut*50 + (c-665)];
}

// ----------------------------------------------------------- pointwise ----
// rel LSTM + m_where/s_where/z_where_i (serial chains, round-3 order)
__global__ __launch_bounds__(256) void lstm_rel_kernel(
    const float* __restrict__ gates,
    float* __restrict__ h_rela, float* __restrict__ c_rela,
    float* __restrict__ x_rel, float* __restrict__ x_tem, float* __restrict__ x_mt,
    const float* __restrict__ zwhere_lt, const float* __restrict__ w_lwhere,
    const float* __restrict__ b_lwhere, const float* __restrict__ eps_where, int t,
    float* __restrict__ m_where, float* __restrict__ s_where,
    float* __restrict__ o_zwhere)
{
  __shared__ float sh[256];
  long item = blockIdx.x;
  int j = threadIdx.x;
  const float* grow = gates + item*1024;
  float ig = grow[j], fg = grow[256+j], gg = grow[512+j], og = grow[768+j];
  long hi = item*256 + j;
  float c  = c_rela[hi];
  float c2 = sigm(fg)*c + sigm(ig)*tanhf(gg);
  float h2 = sigm(og)*tanhf(c2);
  c_rela[hi] = c2;
  h_rela[hi] = h2;
  sh[j] = h2;
  x_tem[item*KTEM + 359 + j] = h2;
  x_tem[item*KTEM + 615 + j] = h2;
  x_mt [item*KMT  +  50 + j] = h2;
  x_rel[item*KREL + 462 + j] = h2;   // for step t+1
  __syncthreads();
  if (j < 3) {
    long ut = item*16 + t;
    const float* wm  = w_lwhere + j*259;
    const float* wsr = w_lwhere + (j+3)*259;
    float am = b_lwhere[j], as = b_lwhere[j+3];
    #pragma unroll
    for (int k = 0; k < 3; k++) {
      float v = zwhere_lt[ut*3 + k];
      am = fmaf(v, wm[k], am);  as = fmaf(v, wsr[k], as);
    }
    for (int k = 0; k < 256; k++) {
      float v = sh[k];
      am = fmaf(v, wm[3+k], am);  as = fmaf(v, wsr[3+k], as);
    }
    float s = softp(as) + 1e-4f;
    float zw = am + s * eps_where[ut*3 + j];
    m_where[item*3 + j] = am;
    s_where[item*3 + j] = s;
    o_zwhere[ut*3 + j]  = zw;
    x_rel[item*KREL + 103 + j] = zw;   // zw_prev for step t+1
  }
}

__global__ void lstm_tem_kernel(const float* __restrict__ gates,
    const float* __restrict__ c_rela, float* __restrict__ o_htemp, int t,
    float* __restrict__ x_mt, float* __restrict__ x_tem,
    const float* __restrict__ o_zwhere)
{
  long idx = (long)blockIdx.x * 256 + threadIdx.x;
  if (idx >= (long)NB*256) return;
  long item = idx >> 8; int j = (int)(idx & 255);
  const float* grow = gates + item*1024;
  float ig = grow[j], fg = grow[256+j], gg = grow[512+j], og = grow[768+j];
  float c  = c_rela[idx];
  float c2 = sigm(fg)*c + sigm(ig)*tanhf(gg);
  float h2 = sigm(og)*tanhf(c2);
  long ut = item*16 + t;
  o_htemp[ut*256 + j] = h2;
  x_mt[item*KMT + 306 + j] = h2;
  if (j < 3) x_tem[item*KTEM + 100 + j] = o_zwhere[ut*3 + j];  // zw_prev for t+1
}

// pres + z_what sampling fused (z_what values identical to round-3 zwhat_kernel)
__global__ __launch_bounds__(256) void pres_kernel(
    const float* __restrict__ o_zwhere,
    const float* __restrict__ h_rela, const float* __restrict__ o_htemp,
    const float* __restrict__ w_lpres, const float* __restrict__ b_lpres,
    const float* __restrict__ zpres_lt, const float* __restrict__ u_pres, int t,
    const float* __restrict__ mt, const float* __restrict__ m_where,
    const float* __restrict__ s_where, const float* __restrict__ eps_what,
    float* __restrict__ o_zwhat, float* __restrict__ x_rel,
    float* __restrict__ o_zpres, float* __restrict__ out_klwhat,
    float* __restrict__ out_klwhere)
{
  int tid = threadIdx.x;
  long item = (long)blockIdx.x*4 + (tid >> 6);
  if (item >= NB) return;
  int l = tid & 63;
  long ut = item*16 + t;
  float part = 0.f;
  for (int c = l; c < 565; c += 64) {
    float x;
    if (c < 50) {
      float m = mt[item*100 + c];
      float s = softp(mt[item*100 + 50 + c]) + 1e-4f;
      x = m + s * eps_what[ut*50 + c];
      o_zwhat[ut*50 + c] = x;
      x_rel[item*KREL + 156 + c] = x;   // zwt_prev for step t+1
    }
    else if (c < 53)  x = o_zwhere[ut*3 + (c-50)];
    else if (c < 309) x = h_rela[item*256 + (c-53)];
    else              x = o_htemp[ut*256 + (c-309)];
    part = fmaf(x, w_lpres[c], part);
  }
  #pragma unroll
  for (int off = 32; off; off >>= 1) part += __shfl_down(part, off);
  float zpres = 0.f;
  if (l == 0) {
    float p = sigm(part + b_lpres[0]);
    zpres = (u_pres[ut] < p * zpres_lt[ut]) ? 1.f : 0.f;
    o_zpres[ut] = zpres;
  }
  float w = __shfl(zpres, 0);
  float kw = 0.f, kwh = 0.f;
  if (l < 50) {
    float m = mt[item*100 + l];
    float s = softp(mt[item*100 + 50 + l]) + 1e-4f;
    kw = -logf(s) + 0.5f*(s*s + m*m) - 0.5f;
  }
  if (l < 3) {
    float m = m_where[item*3 + l], s = s_where[item*3 + l];
    float m0 = (l == 0) ? 0.3f : 0.f;
    float s0 = (l == 0) ? 0.1f : 1.f;
    kwh = logf(s0 / s) + (s*s + (m-m0)*(m-m0)) / (2.f*s0*s0) - 0.5f;
  }
  #pragma unroll
  for (int off = 32; off; off >>= 1) {
    kw  += __shfl_down(kw,  off);
    kwh += __shfl_down(kwh, off);
  }
  if (l == 0) {
    out_klwhat[item]  += w * kw;
    out_klwhere[item] += w * kwh;
  }
}

// ---------------------------------------------------------------- host ----
extern "C" void kernel_launch(void* const* d_in, const int* in_sizes, int n_in,
                              void* d_out, int out_size, void* d_ws, size_t ws_size,
                              hipStream_t stream) {
  (void)in_sizes; (void)n_in; (void)out_size; (void)ws_size;
  const float* img       = (const float*)d_in[0];
  const float* zwhat_lt  = (const float*)d_in[1];
  const float* zwhere_lt = (const float*)d_in[2];
  const float* zpres_lt  = (const float*)d_in[3];
  const float* hid_lt    = (const float*)d_in[4];
  const float* eps_where = (const float*)d_in[5];
  const float* eps_what  = (const float*)d_in[6];
  const float* u_pres    = (const float*)d_in[7];
  const float* w_pro     = (const float*)d_in[8];
  const float* b_pro     = (const float*)d_in[9];
  const float* w_ge1     = (const float*)d_in[10];
  const float* b_ge1     = (const float*)d_in[11];
  const float* w_ge2     = (const float*)d_in[12];
  const float* b_ge2     = (const float*)d_in[13];
  const float* wih_rel   = (const float*)d_in[14];
  const float* whh_rel   = (const float*)d_in[15];
  const float* bih_rel   = (const float*)d_in[16];
  const float* bhh_rel   = (const float*)d_in[17];
  const float* wih_tem   = (const float*)d_in[18];
  const float* whh_tem   = (const float*)d_in[19];
  const float* bih_tem   = (const float*)d_in[20];
  const float* bhh_tem   = (const float*)d_in[21];
  const float* w_lwhere  = (const float*)d_in[22];
  const float* b_lwhere  = (const float*)d_in[23];
  const float* w_lwhat   = (const float*)d_in[24];
  const float* b_lwhat   = (const float*)d_in[25];
  const float* w_lpres   = (const float*)d_in[26];
  const float* b_lpres   = (const float*)d_in[27];

  float* ws = (float*)d_ws;
  float* W_relT   = ws;                       // 737280  (720 x 1024, k-major)
  float* W_temT   = W_relT + 737280;          // 901120  (880 x 1024, k-major)
  float* W_mt     = W_temT + 901120;          // 57600
  float* W_ge2p   = W_mt + 57600;             // 20800
  float* bias_rel = W_ge2p + 20800;           // 1024
  float* bias_tem = bias_rel + 1024;          // 1024
  float* zwb_all  = bias_tem + 1024;          // 196608
  float* enc_all  = zwb_all + 196608;         // 6553600
  float* g_buf    = enc_all + 6553600;        // 6553600 (CH*400)
  float* h1_buf   = g_buf + 6553600;          // 3407872 (CH*208)
  float* x_rel    = h1_buf + 3407872;         // 2949120
  float* x_tem    = x_rel + 2949120;          // 3604480
  float* x_mt     = x_tem + 3604480;          // 2359296
  float* gates    = x_mt + 2359296;           // 4194304
  float* h_rela   = gates + 4194304;          // 1048576
  float* c_rela   = h_rela + 1048576;         // 1048576
  float* m_where  = c_rela + 1048576;         // 12288
  float* s_where  = m_where + 12288;          // 12288
  float* mtbuf    = s_where + 12288;          // 409600

  float* out       = (float*)d_out;
  float* o_zwhat   = out + OUT_ZWHAT;
  float* o_zwhere  = out + OUT_ZWHERE;
  float* o_zpres   = out + OUT_ZPRES;
  float* o_klwhat  = out + OUT_KLWHAT;
  float* o_htemp   = out + OUT_HTEMP;

  prep_kernel<<<63067, 256, 0, stream>>>(wih_rel, whh_rel, bih_rel, bhh_rel,
      wih_tem, whh_tem, bih_tem, bhh_tem, w_lwhat, w_ge2,
      W_relT, W_temT, W_mt, W_ge2p, bias_rel, bias_tem, h_rela, c_rela,
      x_rel, x_tem, x_mt, h1_buf, o_klwhat);

  zwb_kernel<<<4096, 256, 0, stream>>>(hid_lt, zwhere_lt, w_pro, b_pro, zwb_all);

  for (int c = 0; c < 4; c++) {
    gfill_kernel<<<CH/16, 256, 0, stream>>>(img, zwb_all + (long)c*CH*3, 3,
        (long)c*CH, 4, g_buf);
    gemmNK64_kernel<true><<<dim3(CH/64, 4), 256, 0, stream>>>(
        g_buf, 400, w_ge1, 400, b_ge1, h1_buf, KGE2, 400, 200);
    gemmNK64_kernel<false><<<dim3(CH/64, 2), 256, 0, stream>>>(
        h1_buf, KGE2, W_ge2p, KGE2, b_ge2, enc_all + (long)c*CH*100, 100, KGE2, 100);
  }

  for (int t = 0; t < TT; t++) {
    assemble_kernel<<<11440, 256, 0, stream>>>(enc_all, zwhat_lt, zwhere_lt,
        hid_lt, t, x_rel, x_tem, x_mt);
    gemmR_kernel<<<dim3(16, 32), 256, 0, stream>>>(x_rel, KREL, W_relT, NG,
        bias_rel, gates, NG, KREL);
    lstm_rel_kernel<<<4096, 256, 0, stream>>>(gates, h_rela, c_rela,
        x_rel, x_tem, x_mt, zwhere_lt, w_lwhere, b_lwhere, eps_where, t,
        m_where, s_where, o_zwhere);
    gfill_kernel<<<256, 256, 0, stream>>>(img, o_zwhere + t*3, 48, 0, 0, g_buf);
    gemmNK64_kernel<true><<<dim3(64, 4), 256, 0, stream>>>(
        g_buf, 400, w_ge1, 400, b_ge1, h1_buf, KGE2, 400, 200);
    gemmNK64_kernel<false><<<dim3(64, 2), 256, 0, stream>>>(
        h1_buf, KGE2, W_ge2p, KGE2, b_ge2, x_tem, KTEM, KGE2, 100);
    gemmR_kernel<<<dim3(16, 32), 256, 0, stream>>>(x_tem, KTEM, W_temT, NG,
        bias_tem, gates, NG, KTEM);
    lstm_tem_kernel<<<4096, 256, 0, stream>>>(gates, c_rela, o_htemp, t,
        x_mt, x_tem, o_zwhere);
    gemmNK64_kernel<false><<<dim3(64, 2), 256, 0, stream>>>(
        x_mt, KMT, W_mt, KMT, b_lwhat, mtbuf, 100, KMT, 100);
    pres_kernel<<<1024, 256, 0, stream>>>(o_zwhere, h_rela, o_htemp,
        w_lpres, b_lpres, zpres_lt, u_pres, t, mtbuf, m_where, s_where,
        eps_what, o_zwhat, x_rel, o_zpres, o_klwhat, o_klwhat + 4096);
  }
}

// Round 8
// 6108.086 us; speedup vs baseline: 4.6394x; 1.0243x over previous
//
#include <hip/hip_runtime.h>
#include <math.h>

#define DEV __device__ __forceinline__

// NUMERICS FREEZE: every output element keeps round-1's exact fp order:
// one thread per output, fmaf ascending over k, bias added once at the end.
// Only order-preserving optimizations (tiling/occupancy/fusion) allowed.
// Round-2 lesson: any reorder flips a u < p*zp threshold somewhere -> FAIL.
// Round-6 lesson: 8x8 micro pins total waves at 1024 = 1 wave/SIMD.
// Round-7 lesson: 8x4 micro @ 2 waves/SIMD == LDS-pipe floor (~107us).
// Round-8 lesson (gemmG): 64-VGPR operand buffer under the 128-VGPR cap
// -> scratch spill (WRITE_SIZE 2GB, 898us). Keep reg buffers tiny.
// Round-9 lesson (gemmR): v_readlane B costs +25% VALU issue AND 1
// ds_read/k single-outstanding exposes LDS latency at 2 waves/SIMD ->
// 137us, VALUBusy 56%. Fix both: wave-uniform B via scalar loads (no
// VALU, no LDS, no VGPRs) + 4-deep batched ds_read_b128 for MLP.

constexpr int NB    = 4096;
constexpr int TT    = 16;
constexpr int KREL  = 720;   // [enc 100 | zwr 3 | zw_prev 3 | zwt_l 50 | zwt_prev 50 | hid 256 | h 256 | pad 2]
constexpr int KTEM  = 880;   // [enc 100 | zw_prev 3 | hid 256 | h 256 | h(whh) 256 | pad 9]
constexpr int KMT   = 576;   // [zwt_l 50 | h_rela 256 | h_temp 256 | pad 14]
constexpr int KGE2  = 208;   // 200 padded
constexpr int NG    = 1024;
constexpr int CH    = 16384; // enc chunk units

constexpr long OUT_ZWHAT   = 0L;
constexpr long OUT_ZWHERE  = 3276800L;
constexpr long OUT_ZPRES   = 3473408L;
constexpr long OUT_KLWHAT  = 3538944L;
constexpr long OUT_HTEMP   = 3547136L;

DEV float sigm(float x)  { return 1.f / (1.f + expf(-x)); }
DEV float softp(float x) { return fmaxf(x, 0.f) + log1pf(expf(-fabsf(x))); }

// ---------------------------------------------------------------- prep ----
// W_relT/W_temT are k-major (transposed): W*T[k][n], n contiguous.
__global__ void prep_kernel(
    const float* __restrict__ wih_rel, const float* __restrict__ whh_rel,
    const float* __restrict__ bih_rel, const float* __restrict__ bhh_rel,
    const float* __restrict__ wih_tem, const float* __restrict__ whh_tem,
    const float* __restrict__ bih_tem, const float* __restrict__ bhh_tem,
    const float* __restrict__ w_lwhat, const float* __restrict__ w_ge2,
    float* __restrict__ W_relT, float* __restrict__ W_temT, float* __restrict__ W_mt,
    float* __restrict__ W_ge2p,
    float* __restrict__ bias_rel, float* __restrict__ bias_tem,
    float* __restrict__ h_rela, float* __restrict__ c_rela,
    float* __restrict__ x_rel, float* __restrict__ x_tem, float* __restrict__ x_mt,
    float* __restrict__ h1_buf, float* __restrict__ out_kl)
{
  long idx = (long)blockIdx.x * 256 + threadIdx.x;
  if (idx < 737280) { int k = (int)(idx >> 10), j = (int)(idx & 1023);
    W_relT[idx] = (k < 462) ? wih_rel[j*462+k] : (k < 718 ? whh_rel[j*256 + (k-462)] : 0.f); return; }
  idx -= 737280;
  if (idx < 901120) { int k = (int)(idx >> 10), j = (int)(idx & 1023);
    W_temT[idx] = (k < 615) ? wih_tem[j*615+k] : (k < 871 ? whh_tem[j*256 + (k-615)] : 0.f); return; }
  idx -= 901120;
  if (idx < 57600) { int j = (int)(idx/576), k = (int)(idx - (long)j*576);
    W_mt[idx] = (k < 562) ? w_lwhat[j*562+k] : 0.f; return; }
  idx -= 57600;
  if (idx < 20800) { int j = (int)(idx/208), k = (int)(idx - (long)j*208);
    W_ge2p[idx] = (k < 200) ? w_ge2[j*200+k] : 0.f; return; }
  idx -= 20800;
  if (idx < 1024) { bias_rel[idx] = bih_rel[idx] + bhh_rel[idx]; return; }
  idx -= 1024;
  if (idx < 1024) { bias_tem[idx] = bih_tem[idx] + bhh_tem[idx]; return; }
  idx -= 1024;
  if (idx < 1048576) { h_rela[idx] = 0.f; return; }
  idx -= 1048576;
  if (idx < 1048576) { c_rela[idx] = 0.f; return; }
  idx -= 1048576;
  if (idx < 2949120) { x_rel[idx] = 0.f; return; }
  idx -= 2949120;
  if (idx < 3604480) { x_tem[idx] = 0.f; return; }
  idx -= 3604480;
  if (idx < 2359296) { x_mt[idx] = 0.f; return; }
  idx -= 2359296;
  if (idx < 3407872) { h1_buf[idx] = 0.f; return; }
  idx -= 3407872;
  if (idx < 8192) { out_kl[idx] = 0.f; return; }
}

// z_where_bias for all 65536 units (round-1 reduction order)
__global__ __launch_bounds__(256) void zwb_kernel(
    const float* __restrict__ hid_all, const float* __restrict__ zwr_all,
    const float* __restrict__ w_pro, const float* __restrict__ b_pro,
    float* __restrict__ zwb_all)
{
  int tid = threadIdx.x;
  long unit0 = (long)blockIdx.x * 16;
  int u = tid >> 4, l = tid & 15;
  const float* hid = hid_all + (unit0 + u) * 256;
  float p0 = 0.f, p1 = 0.f, p2 = 0.f;
  for (int k = l; k < 256; k += 16) {
    float h = hid[k];
    p0 = fmaf(h, w_pro[k],       p0);
    p1 = fmaf(h, w_pro[256 + k], p1);
    p2 = fmaf(h, w_pro[512 + k], p2);
  }
  #pragma unroll
  for (int off = 8; off; off >>= 1) {
    p0 += __shfl_down(p0, off, 16);
    p1 += __shfl_down(p1, off, 16);
    p2 += __shfl_down(p2, off, 16);
  }
  if (l == 0) {
    long unit = unit0 + u;
    zwb_all[unit*3+0] = fmaxf(p0 + b_pro[0], 0.f) + zwr_all[unit*3+0];
    zwb_all[unit*3+1] = fmaxf(p1 + b_pro[1], 0.f) + zwr_all[unit*3+1];
    zwb_all[unit*3+2] = fmaxf(p2 + b_pro[2], 0.f) + zwr_all[unit*3+2];
  }
}

// ------------------------------------------------------------- glimpse ----
DEV float bilin_sample(const float* im, int y, int x) {
  bool valid = ((unsigned)x < 50u) && ((unsigned)y < 50u);
  int yc = min(max(y, 0), 49), xc = min(max(x, 0), 49);
  float v = im[yc*50 + xc];
  return valid ? v : 0.f;
}

__global__ __launch_bounds__(256) void gfill_kernel(
    const float* __restrict__ img, const float* __restrict__ zwbp, int zstride,
    long ibase, int shift, float* __restrict__ g_out)
{
  __shared__ float zwb[16][3];
  int tid = threadIdx.x;
  long unit0 = (long)blockIdx.x * 16;
  if (tid < 48) {
    int u = tid / 3, j = tid - u*3;
    zwb[u][j] = zwbp[(unit0 + u)*(long)zstride + j];
  }
  __syncthreads();
  for (int p = tid; p < 16*400; p += 256) {
    int u = p / 400, pix = p - u*400;
    long item = (ibase + unit0 + u) >> shift;
    float s = zwb[u][0], tx = zwb[u][1], ty = zwb[u][2];
    int iyi = pix / 20, ixi = pix - iyi*20;
    float bx = (2.f*ixi + 1.f)/20.f - 1.f;
    float by = (2.f*iyi + 1.f)/20.f - 1.f;
    float x = s*bx + tx, y = s*by + ty;
    float ix = ((x + 1.f)*50.f - 1.f)*0.5f;
    float iy = ((y + 1.f)*50.f - 1.f)*0.5f;
    float x0f = floorf(ix), y0f = floorf(iy);
    float wx = ix - x0f, wy = iy - y0f;
    int x0 = (int)x0f, y0 = (int)y0f;
    const float* im = img + item*2500;
    float v00 = bilin_sample(im, y0,   x0  );
    float v01 = bilin_sample(im, y0,   x0+1);
    float v10 = bilin_sample(im, y0+1, x0  );
    float v11 = bilin_sample(im, y0+1, x0+1);
    g_out[(unit0+u)*400 + pix] = v00*(1.f-wx)*(1.f-wy) + v01*wx*(1.f-wy)
                               + v10*(1.f-wx)*wy       + v11*wx*wy;
  }
}

// --------------------------------------------------------------- GEMMs ----
// Big-gate GEMM, round-10 "gemmS": 256x32 tile, 256 threads, 4x8 micro,
// 2 wgs/CU (2 waves/SIMD). Wave w owns cols c0=n0+8w (wave-UNIFORM);
// lane l owns rows m0+4l..+3.
//   A: LDS [k][m], ds_read_b128 per k, batched 4-deep per group for MLP
//      (round-9 lesson: 1 read/k single-outstanding exposes ~120cyc LDS
//      latency at 2 waves/SIMD).
//   B: wave-uniform scalar loads from L2-resident W (readfirstlane-forced
//      uniform base -> s_load path). No LDS, no VALU tax, no VGPR buffer
//      (round-8/9 lessons). fma consumes b as its one SGPR operand.
// Per-output order: fmaf ascending k (groups ascend, b0->b3 inside group),
// bias last -> bit-identical.
__global__ __launch_bounds__(256, 2) void gemmS_kernel(
    const float* __restrict__ A, int lda,
    const float* __restrict__ Wt, int ldwt,
    const float* __restrict__ bias,
    float* __restrict__ C, int ldc, int K)
{
  __shared__ float As[2][16][256];
  int tid  = threadIdx.x;
  int lane = tid & 63;
  int m0 = blockIdx.x << 8;           // 256-row tile
  int n0 = blockIdx.y << 5;           // 32-col tile
  int c0 = n0 + ((tid >> 6) << 3);    // this wave's 8 columns
  int c0u = n0 + ((__builtin_amdgcn_readfirstlane(tid) >> 6) << 3); // uniform
  const float* Ap = A + (long)(m0 + tid)*lda;   // this thread's A row
  const float* Bu = Wt + c0u;                   // wave-uniform B base
  float acc[4][8] = {};

  // prologue: tile 0 -> LDS buf 0
  float4 pa0 = *(const float4*)(Ap + 0);
  float4 pa1 = *(const float4*)(Ap + 4);
  float4 pa2 = *(const float4*)(Ap + 8);
  float4 pa3 = *(const float4*)(Ap + 12);
  As[0][ 0][tid]=pa0.x; As[0][ 1][tid]=pa0.y; As[0][ 2][tid]=pa0.z; As[0][ 3][tid]=pa0.w;
  As[0][ 4][tid]=pa1.x; As[0][ 5][tid]=pa1.y; As[0][ 6][tid]=pa1.z; As[0][ 7][tid]=pa1.w;
  As[0][ 8][tid]=pa2.x; As[0][ 9][tid]=pa2.y; As[0][10][tid]=pa2.z; As[0][11][tid]=pa2.w;
  As[0][12][tid]=pa3.x; As[0][13][tid]=pa3.y; As[0][14][tid]=pa3.z; As[0][15][tid]=pa3.w;
  __syncthreads();

  int buf = 0;
  for (int k0 = 16;; k0 += 16) {
    int kc = k0 - 16;                 // current tile's k base
    bool more = k0 < K;
    if (more) {
      pa0 = *(const float4*)(Ap + k0);
      pa1 = *(const float4*)(Ap + k0 + 4);
      pa2 = *(const float4*)(Ap + k0 + 8);
      pa3 = *(const float4*)(Ap + k0 + 12);
    }
    #pragma unroll
    for (int g = 0; g < 4; g++) {
      // 4 ds_read_b128 issued together -> 4 outstanding (MLP)
      float4 av0 = *(const float4*)&As[buf][g*4+0][lane << 2];
      float4 av1 = *(const float4*)&As[buf][g*4+1][lane << 2];
      float4 av2 = *(const float4*)&As[buf][g*4+2][lane << 2];
      float4 av3 = *(const float4*)&As[buf][g*4+3][lane << 2];
      float a0[4] = {av0.x,av0.y,av0.z,av0.w};
      float a1[4] = {av1.x,av1.y,av1.z,av1.w};
      float a2[4] = {av2.x,av2.y,av2.z,av2.w};
      float a3[4] = {av3.x,av3.y,av3.z,av3.w};
      const float* B0 = Bu + (long)(kc + g*4 + 0)*ldwt;
      const float* B1 = Bu + (long)(kc + g*4 + 1)*ldwt;
      const float* B2 = Bu + (long)(kc + g*4 + 2)*ldwt;
      const float* B3 = Bu + (long)(kc + g*4 + 3)*ldwt;
      #pragma unroll
      for (int j = 0; j < 8; j++) {
        float b0 = B0[j], b1 = B1[j], b2 = B2[j], b3 = B3[j];
        #pragma unroll
        for (int i = 0; i < 4; i++) {
          // k ascending per output: g*4+0, +1, +2, +3
          acc[i][j] = fmaf(a0[i], b0, acc[i][j]);
          acc[i][j] = fmaf(a1[i], b1, acc[i][j]);
          acc[i][j] = fmaf(a2[i], b2, acc[i][j]);
          acc[i][j] = fmaf(a3[i], b3, acc[i][j]);
        }
      }
    }
    if (!more) break;
    buf ^= 1;
    As[buf][ 0][tid]=pa0.x; As[buf][ 1][tid]=pa0.y; As[buf][ 2][tid]=pa0.z; As[buf][ 3][tid]=pa0.w;
    As[buf][ 4][tid]=pa1.x; As[buf][ 5][tid]=pa1.y; As[buf][ 6][tid]=pa1.z; As[buf][ 7][tid]=pa1.w;
    As[buf][ 8][tid]=pa2.x; As[buf][ 9][tid]=pa2.y; As[buf][10][tid]=pa2.z; As[buf][11][tid]=pa2.w;
    As[buf][12][tid]=pa3.x; As[buf][13][tid]=pa3.y; As[buf][14][tid]=pa3.z; As[buf][15][tid]=pa3.w;
    __syncthreads();
  }

  float bj[8];
  #pragma unroll
  for (int j = 0; j < 8; j++) bj[j] = bias[c0 + j];
  #pragma unroll
  for (int i = 0; i < 4; i++) {
    int mi = m0 + (lane << 2) + i;
    float* Crow = C + (long)mi*ldc + c0;
    float4 v0 = make_float4(acc[i][0]+bj[0], acc[i][1]+bj[1],
                            acc[i][2]+bj[2], acc[i][3]+bj[3]);
    float4 v1 = make_float4(acc[i][4]+bj[4], acc[i][5]+bj[5],
                            acc[i][6]+bj[6], acc[i][7]+bj[7]);
    *(float4*)(Crow)     = v0;
    *(float4*)(Crow + 4) = v1;
  }
}

// 64x64 tile, 4x4 micro, N-bounded, optional ReLU. K % 16 == 0 REQUIRED.
template<bool RELU>
__global__ __launch_bounds__(256) void gemmNK64_kernel(
    const float* __restrict__ A, int lda,
    const float* __restrict__ W, int ldw,
    const float* __restrict__ bias,
    float* __restrict__ C, int ldc, int K, int N)
{
  __shared__ float As[16][68];
  __shared__ float Bs[16][68];
  int tid = threadIdx.x;
  int m0 = blockIdx.x << 6, n0 = blockIdx.y << 6;
  int r  = tid >> 2;
  int kq = (tid & 3) << 2;
  const float* Ap = A + (long)(m0 + r)*lda + kq;
  const float* Wp = W + (long)(n0 + r)*ldw + kq;
  bool wv = (n0 + r) < N;
  int tm = (tid & 15) << 2;
  int tn = ((tid >> 4) & 15) << 2;
  float acc[4][4] = {};
  float4 a0 = *(const float4*)Ap;
  float4 b0 = wv ? *(const float4*)Wp : make_float4(0.f,0.f,0.f,0.f);
  for (int k0 = 16;; k0 += 16) {
    __syncthreads();
    As[kq+0][r]=a0.x; As[kq+1][r]=a0.y; As[kq+2][r]=a0.z; As[kq+3][r]=a0.w;
    Bs[kq+0][r]=b0.x; Bs[kq+1][r]=b0.y; Bs[kq+2][r]=b0.z; Bs[kq+3][r]=b0.w;
    __syncthreads();
    if (k0 < K) {
      a0 = *(const float4*)(Ap + k0);
      b0 = wv ? *(const float4*)(Wp + k0) : make_float4(0.f,0.f,0.f,0.f);
    }
    #pragma unroll
    for (int k = 0; k < 16; k++) {
      float4 av = *(const float4*)&As[k][tm];
      float4 bv = *(const float4*)&Bs[k][tn];
      float a[4] = {av.x,av.y,av.z,av.w};
      float b[4] = {bv.x,bv.y,bv.z,bv.w};
      #pragma unroll
      for (int i = 0; i < 4; i++)
        #pragma unroll
        for (int j = 0; j < 4; j++)
          acc[i][j] = fmaf(a[i], b[j], acc[i][j]);
    }
    if (k0 >= K) break;
  }
  #pragma unroll
  for (int i = 0; i < 4; i++) {
    int mi = m0 + tm + i;
    float* Crow = C + (long)mi*ldc + n0;
    #pragma unroll
    for (int j = 0; j < 4; j++) {
      int nj = tn + j;
      if (n0 + nj < N) {
        float v = acc[i][j] + bias[n0 + nj];
        if (RELU) v = fmaxf(v, 0.f);
        Crow[nj] = v;
      }
    }
  }
}

// ------------------------------------------------------------ assemble ----
__global__ void assemble_kernel(
    const float* __restrict__ enc_all, const float* __restrict__ zwhat_lt,
    const float* __restrict__ zwhere_lt, const float* __restrict__ hid_lt, int t,
    float* __restrict__ x_rel, float* __restrict__ x_tem, float* __restrict__ x_mt)
{
  long idx = (long)blockIdx.x * 256 + threadIdx.x;
  const int PER = 715;
  long item = idx / PER;
  int c = (int)(idx - item*PER);
  if (item >= NB) return;
  long ut = item*16 + t;
  if (c < 100)      x_rel[item*KREL + c]             = enc_all[ut*100 + c];
  else if (c < 103) x_rel[item*KREL + 100 + (c-100)] = zwhere_lt[ut*3 + (c-100)];
  else if (c < 153) x_rel[item*KREL + 106 + (c-103)] = zwhat_lt[ut*50 + (c-103)];
  else if (c < 409) x_rel[item*KREL + 206 + (c-153)] = hid_lt[ut*256 + (c-153)];
  else if (c < 665) x_tem[item*KTEM + 103 + (c-409)] = hid_lt[ut*256 + (c-409)];
  else              x_mt [item*KMT  + (c-665)]       = zwhat_lt[ut*50 + (c-665)];
}

// ----------------------------------------------------------- pointwise ----
// rel LSTM + m_where/s_where/z_where_i (serial chains, round-3 order)
__global__ __launch_bounds__(256) void lstm_rel_kernel(
    const float* __restrict__ gates,
    float* __restrict__ h_rela, float* __restrict__ c_rela,
    float* __restrict__ x_rel, float* __restrict__ x_tem, float* __restrict__ x_mt,
    const float* __restrict__ zwhere_lt, const float* __restrict__ w_lwhere,
    const float* __restrict__ b_lwhere, const float* __restrict__ eps_where, int t,
    float* __restrict__ m_where, float* __restrict__ s_where,
    float* __restrict__ o_zwhere)
{
  __shared__ float sh[256];
  long item = blockIdx.x;
  int j = threadIdx.x;
  const float* grow = gates + item*1024;
  float ig = grow[j], fg = grow[256+j], gg = grow[512+j], og = grow[768+j];
  long hi = item*256 + j;
  float c  = c_rela[hi];
  float c2 = sigm(fg)*c + sigm(ig)*tanhf(gg);
  float h2 = sigm(og)*tanhf(c2);
  c_rela[hi] = c2;
  h_rela[hi] = h2;
  sh[j] = h2;
  x_tem[item*KTEM + 359 + j] = h2;
  x_tem[item*KTEM + 615 + j] = h2;
  x_mt [item*KMT  +  50 + j] = h2;
  x_rel[item*KREL + 462 + j] = h2;   // for step t+1
  __syncthreads();
  if (j < 3) {
    long ut = item*16 + t;
    const float* wm  = w_lwhere + j*259;
    const float* wsr = w_lwhere + (j+3)*259;
    float am = b_lwhere[j], as = b_lwhere[j+3];
    #pragma unroll
    for (int k = 0; k < 3; k++) {
      float v = zwhere_lt[ut*3 + k];
      am = fmaf(v, wm[k], am);  as = fmaf(v, wsr[k], as);
    }
    for (int k = 0; k < 256; k++) {
      float v = sh[k];
      am = fmaf(v, wm[3+k], am);  as = fmaf(v, wsr[3+k], as);
    }
    float s = softp(as) + 1e-4f;
    float zw = am + s * eps_where[ut*3 + j];
    m_where[item*3 + j] = am;
    s_where[item*3 + j] = s;
    o_zwhere[ut*3 + j]  = zw;
    x_rel[item*KREL + 103 + j] = zw;   // zw_prev for step t+1
  }
}

__global__ void lstm_tem_kernel(const float* __restrict__ gates,
    const float* __restrict__ c_rela, float* __restrict__ o_htemp, int t,
    float* __restrict__ x_mt, float* __restrict__ x_tem,
    const float* __restrict__ o_zwhere)
{
  long idx = (long)blockIdx.x * 256 + threadIdx.x;
  if (idx >= (long)NB*256) return;
  long item = idx >> 8; int j = (int)(idx & 255);
  const float* grow = gates + item*1024;
  float ig = grow[j], fg = grow[256+j], gg = grow[512+j], og = grow[768+j];
  float c  = c_rela[idx];
  float c2 = sigm(fg)*c + sigm(ig)*tanhf(gg);
  float h2 = sigm(og)*tanhf(c2);
  long ut = item*16 + t;
  o_htemp[ut*256 + j] = h2;
  x_mt[item*KMT + 306 + j] = h2;
  if (j < 3) x_tem[item*KTEM + 100 + j] = o_zwhere[ut*3 + j];  // zw_prev for t+1
}

// pres + z_what sampling fused (z_what values identical to round-3 zwhat_kernel)
__global__ __launch_bounds__(256) void pres_kernel(
    const float* __restrict__ o_zwhere,
    const float* __restrict__ h_rela, const float* __restrict__ o_htemp,
    const float* __restrict__ w_lpres, const float* __restrict__ b_lpres,
    const float* __restrict__ zpres_lt, const float* __restrict__ u_pres, int t,
    const float* __restrict__ mt, const float* __restrict__ m_where,
    const float* __restrict__ s_where, const float* __restrict__ eps_what,
    float* __restrict__ o_zwhat, float* __restrict__ x_rel,
    float* __restrict__ o_zpres, float* __restrict__ out_klwhat,
    float* __restrict__ out_klwhere)
{
  int tid = threadIdx.x;
  long item = (long)blockIdx.x*4 + (tid >> 6);
  if (item >= NB) return;
  int l = tid & 63;
  long ut = item*16 + t;
  float part = 0.f;
  for (int c = l; c < 565; c += 64) {
    float x;
    if (c < 50) {
      float m = mt[item*100 + c];
      float s = softp(mt[item*100 + 50 + c]) + 1e-4f;
      x = m + s * eps_what[ut*50 + c];
      o_zwhat[ut*50 + c] = x;
      x_rel[item*KREL + 156 + c] = x;   // zwt_prev for step t+1
    }
    else if (c < 53)  x = o_zwhere[ut*3 + (c-50)];
    else if (c < 309) x = h_rela[item*256 + (c-53)];
    else              x = o_htemp[ut*256 + (c-309)];
    part = fmaf(x, w_lpres[c], part);
  }
  #pragma unroll
  for (int off = 32; off; off >>= 1) part += __shfl_down(part, off);
  float zpres = 0.f;
  if (l == 0) {
    float p = sigm(part + b_lpres[0]);
    zpres = (u_pres[ut] < p * zpres_lt[ut]) ? 1.f : 0.f;
    o_zpres[ut] = zpres;
  }
  float w = __shfl(zpres, 0);
  float kw = 0.f, kwh = 0.f;
  if (l < 50) {
    float m = mt[item*100 + l];
    float s = softp(mt[item*100 + 50 + l]) + 1e-4f;
    kw = -logf(s) + 0.5f*(s*s + m*m) - 0.5f;
  }
  if (l < 3) {
    float m = m_where[item*3 + l], s = s_where[item*3 + l];
    float m0 = (l == 0) ? 0.3f : 0.f;
    float s0 = (l == 0) ? 0.1f : 1.f;
    kwh = logf(s0 / s) + (s*s + (m-m0)*(m-m0)) / (2.f*s0*s0) - 0.5f;
  }
  #pragma unroll
  for (int off = 32; off; off >>= 1) {
    kw  += __shfl_down(kw,  off);
    kwh += __shfl_down(kwh, off);
  }
  if (l == 0) {
    out_klwhat[item]  += w * kw;
    out_klwhere[item] += w * kwh;
  }
}

// ---------------------------------------------------------------- host ----
extern "C" void kernel_launch(void* const* d_in, const int* in_sizes, int n_in,
                              void* d_out, int out_size, void* d_ws, size_t ws_size,
                              hipStream_t stream) {
  (void)in_sizes; (void)n_in; (void)out_size; (void)ws_size;
  const float* img       = (const float*)d_in[0];
  const float* zwhat_lt  = (const float*)d_in[1];
  const float* zwhere_lt = (const float*)d_in[2];
  const float* zpres_lt  = (const float*)d_in[3];
  const float* hid_lt    = (const float*)d_in[4];
  const float* eps_where = (const float*)d_in[5];
  const float* eps_what  = (const float*)d_in[6];
  const float* u_pres    = (const float*)d_in[7];
  const float* w_pro     = (const float*)d_in[8];
  const float* b_pro     = (const float*)d_in[9];
  const float* w_ge1     = (const float*)d_in[10];
  const float* b_ge1     = (const float*)d_in[11];
  const float* w_ge2     = (const float*)d_in[12];
  const float* b_ge2     = (const float*)d_in[13];
  const float* wih_rel   = (const float*)d_in[14];
  const float* whh_rel   = (const float*)d_in[15];
  const float* bih_rel   = (const float*)d_in[16];
  const float* bhh_rel   = (const float*)d_in[17];
  const float* wih_tem   = (const float*)d_in[18];
  const float* whh_tem   = (const float*)d_in[19];
  const float* bih_tem   = (const float*)d_in[20];
  const float* bhh_tem   = (const float*)d_in[21];
  const float* w_lwhere  = (const float*)d_in[22];
  const float* b_lwhere  = (const float*)d_in[23];
  const float* w_lwhat   = (const float*)d_in[24];
  const float* b_lwhat   = (const float*)d_in[25];
  const float* w_lpres   = (const float*)d_in[26];
  const float* b_lpres   = (const float*)d_in[27];

  float* ws = (float*)d_ws;
  float* W_relT   = ws;                       // 737280  (720 x 1024, k-major)
  float* W_temT   = W_relT + 737280;          // 901120  (880 x 1024, k-major)
  float* W_mt     = W_temT + 901120;          // 57600
  float* W_ge2p   = W_mt + 57600;             // 20800
  float* bias_rel = W_ge2p + 20800;           // 1024
  float* bias_tem = bias_rel + 1024;          // 1024
  float* zwb_all  = bias_tem + 1024;          // 196608
  float* enc_all  = zwb_all + 196608;         // 6553600
  float* g_buf    = enc_all + 6553600;        // 6553600 (CH*400)
  float* h1_buf   = g_buf + 6553600;          // 3407872 (CH*208)
  float* x_rel    = h1_buf + 3407872;         // 2949120
  float* x_tem    = x_rel + 2949120;          // 3604480
  float* x_mt     = x_tem + 3604480;          // 2359296
  float* gates    = x_mt + 2359296;           // 4194304
  float* h_rela   = gates + 4194304;          // 1048576
  float* c_rela   = h_rela + 1048576;         // 1048576
  float* m_where  = c_rela + 1048576;         // 12288
  float* s_where  = m_where + 12288;          // 12288
  float* mtbuf    = s_where + 12288;          // 409600

  float* out       = (float*)d_out;
  float* o_zwhat   = out + OUT_ZWHAT;
  float* o_zwhere  = out + OUT_ZWHERE;
  float* o_zpres   = out + OUT_ZPRES;
  float* o_klwhat  = out + OUT_KLWHAT;
  float* o_htemp   = out + OUT_HTEMP;

  prep_kernel<<<63067, 256, 0, stream>>>(wih_rel, whh_rel, bih_rel, bhh_rel,
      wih_tem, whh_tem, bih_tem, bhh_tem, w_lwhat, w_ge2,
      W_relT, W_temT, W_mt, W_ge2p, bias_rel, bias_tem, h_rela, c_rela,
      x_rel, x_tem, x_mt, h1_buf, o_klwhat);

  zwb_kernel<<<4096, 256, 0, stream>>>(hid_lt, zwhere_lt, w_pro, b_pro, zwb_all);

  for (int c = 0; c < 4; c++) {
    gfill_kernel<<<CH/16, 256, 0, stream>>>(img, zwb_all + (long)c*CH*3, 3,
        (long)c*CH, 4, g_buf);
    gemmNK64_kernel<true><<<dim3(CH/64, 4), 256, 0, stream>>>(
        g_buf, 400, w_ge1, 400, b_ge1, h1_buf, KGE2, 400, 200);
    gemmNK64_kernel<false><<<dim3(CH/64, 2), 256, 0, stream>>>(
        h1_buf, KGE2, W_ge2p, KGE2, b_ge2, enc_all + (long)c*CH*100, 100, KGE2, 100);
  }

  for (int t = 0; t < TT; t++) {
    assemble_kernel<<<11440, 256, 0, stream>>>(enc_all, zwhat_lt, zwhere_lt,
        hid_lt, t, x_rel, x_tem, x_mt);
    gemmS_kernel<<<dim3(16, 32), 256, 0, stream>>>(x_rel, KREL, W_relT, NG,
        bias_rel, gates, NG, KREL);
    lstm_rel_kernel<<<4096, 256, 0, stream>>>(gates, h_rela, c_rela,
        x_rel, x_tem, x_mt, zwhere_lt, w_lwhere, b_lwhere, eps_where, t,
        m_where, s_where, o_zwhere);
    gfill_kernel<<<256, 256, 0, stream>>>(img, o_zwhere + t*3, 48, 0, 0, g_buf);
    gemmNK64_kernel<true><<<dim3(64, 4), 256, 0, stream>>>(
        g_buf, 400, w_ge1, 400, b_ge1, h1_buf, KGE2, 400, 200);
    gemmNK64_kernel<false><<<dim3(64, 2), 256, 0, stream>>>(
        h1_buf, KGE2, W_ge2p, KGE2, b_ge2, x_tem, KTEM, KGE2, 100);
    gemmS_kernel<<<dim3(16, 32), 256, 0, stream>>>(x_tem, KTEM, W_temT, NG,
        bias_tem, gates, NG, KTEM);
    lstm_tem_kernel<<<4096, 256, 0, stream>>>(gates, c_rela, o_htemp, t,
        x_mt, x_tem, o_zwhere);
    gemmNK64_kernel<false><<<dim3(64, 2), 256, 0, stream>>>(
        x_mt, KMT, W_mt, KMT, b_lwhat, mtbuf, 100, KMT, 100);
    pres_kernel<<<1024, 256, 0, stream>>>(o_zwhere, h_rela, o_htemp,
        w_lpres, b_lpres, zpres_lt, u_pres, t, mtbuf, m_where, s_where,
        eps_what, o_zwhat, x_rel, o_zpres, o_klwhat, o_klwhat + 4096);
  }
}

// Round 9
// 5777.037 us; speedup vs baseline: 4.9053x; 1.0573x over previous
//
#include <hip/hip_runtime.h>
#include <math.h>

#define DEV __device__ __forceinline__

// NUMERICS FREEZE: every output element keeps round-1's exact fp order:
// one thread per output, fmaf ascending over k, bias added once at the end.
// Only order-preserving optimizations (tiling/occupancy/fusion) allowed.
// Round-2 lesson: any reorder flips a u < p*zp threshold somewhere -> FAIL.
// Round-6 lesson: 8x8 micro pins total waves at 1024 = 1 wave/SIMD.
// Round-7 lesson: 8x4 micro @ 2 waves/SIMD == LDS-pipe floor (~107us).
// Round-8 lesson (gemmG): 64-VGPR operand buffer under the 128-VGPR cap
// -> scratch spill (WRITE_SIZE 2GB, 898us). Keep reg buffers tiny.
// Round-9 lesson (gemmR): v_readlane B costs +25% VALU issue; 1 ds_read/k
// single-outstanding exposes LDS latency at 2 waves/SIMD (137us).
// Round-10 lesson (gemmS): wave-uniform s_load B misses L2 (FETCH 21->35MB)
// -> ~900cyc HBM latency per group, unhideable at 2 waves/SIMD (129us,
// VALUBusy 41% == pure fma floor + stall). B must come from LDS.
// This round (gemmT): B in LDS, read via UNIFORM-address b128 (all lanes
// same addr -> HW broadcast, ~16B unique vs 1024B scattered). A stays
// 1 ds_read_b128/k (minimum). Group-of-4 k-batching for MLP.

constexpr int NB    = 4096;
constexpr int TT    = 16;
constexpr int KREL  = 720;   // [enc 100 | zwr 3 | zw_prev 3 | zwt_l 50 | zwt_prev 50 | hid 256 | h 256 | pad 2]
constexpr int KTEM  = 880;   // [enc 100 | zw_prev 3 | hid 256 | h 256 | h(whh) 256 | pad 9]
constexpr int KMT   = 576;   // [zwt_l 50 | h_rela 256 | h_temp 256 | pad 14]
constexpr int KGE2  = 208;   // 200 padded
constexpr int NG    = 1024;
constexpr int CH    = 16384; // enc chunk units

constexpr long OUT_ZWHAT   = 0L;
constexpr long OUT_ZWHERE  = 3276800L;
constexpr long OUT_ZPRES   = 3473408L;
constexpr long OUT_KLWHAT  = 3538944L;
constexpr long OUT_HTEMP   = 3547136L;

DEV float sigm(float x)  { return 1.f / (1.f + expf(-x)); }
DEV float softp(float x) { return fmaxf(x, 0.f) + log1pf(expf(-fabsf(x))); }

// ---------------------------------------------------------------- prep ----
// W_relT/W_temT are k-major (transposed): W*T[k][n], n contiguous.
__global__ void prep_kernel(
    const float* __restrict__ wih_rel, const float* __restrict__ whh_rel,
    const float* __restrict__ bih_rel, const float* __restrict__ bhh_rel,
    const float* __restrict__ wih_tem, const float* __restrict__ whh_tem,
    const float* __restrict__ bih_tem, const float* __restrict__ bhh_tem,
    const float* __restrict__ w_lwhat, const float* __restrict__ w_ge2,
    float* __restrict__ W_relT, float* __restrict__ W_temT, float* __restrict__ W_mt,
    float* __restrict__ W_ge2p,
    float* __restrict__ bias_rel, float* __restrict__ bias_tem,
    float* __restrict__ h_rela, float* __restrict__ c_rela,
    float* __restrict__ x_rel, float* __restrict__ x_tem, float* __restrict__ x_mt,
    float* __restrict__ h1_buf, float* __restrict__ out_kl)
{
  long idx = (long)blockIdx.x * 256 + threadIdx.x;
  if (idx < 737280) { int k = (int)(idx >> 10), j = (int)(idx & 1023);
    W_relT[idx] = (k < 462) ? wih_rel[j*462+k] : (k < 718 ? whh_rel[j*256 + (k-462)] : 0.f); return; }
  idx -= 737280;
  if (idx < 901120) { int k = (int)(idx >> 10), j = (int)(idx & 1023);
    W_temT[idx] = (k < 615) ? wih_tem[j*615+k] : (k < 871 ? whh_tem[j*256 + (k-615)] : 0.f); return; }
  idx -= 901120;
  if (idx < 57600) { int j = (int)(idx/576), k = (int)(idx - (long)j*576);
    W_mt[idx] = (k < 562) ? w_lwhat[j*562+k] : 0.f; return; }
  idx -= 57600;
  if (idx < 20800) { int j = (int)(idx/208), k = (int)(idx - (long)j*208);
    W_ge2p[idx] = (k < 200) ? w_ge2[j*200+k] : 0.f; return; }
  idx -= 20800;
  if (idx < 1024) { bias_rel[idx] = bih_rel[idx] + bhh_rel[idx]; return; }
  idx -= 1024;
  if (idx < 1024) { bias_tem[idx] = bih_tem[idx] + bhh_tem[idx]; return; }
  idx -= 1024;
  if (idx < 1048576) { h_rela[idx] = 0.f; return; }
  idx -= 1048576;
  if (idx < 1048576) { c_rela[idx] = 0.f; return; }
  idx -= 1048576;
  if (idx < 2949120) { x_rel[idx] = 0.f; return; }
  idx -= 2949120;
  if (idx < 3604480) { x_tem[idx] = 0.f; return; }
  idx -= 3604480;
  if (idx < 2359296) { x_mt[idx] = 0.f; return; }
  idx -= 2359296;
  if (idx < 3407872) { h1_buf[idx] = 0.f; return; }
  idx -= 3407872;
  if (idx < 8192) { out_kl[idx] = 0.f; return; }
}

// z_where_bias for all 65536 units (round-1 reduction order)
__global__ __launch_bounds__(256) void zwb_kernel(
    const float* __restrict__ hid_all, const float* __restrict__ zwr_all,
    const float* __restrict__ w_pro, const float* __restrict__ b_pro,
    float* __restrict__ zwb_all)
{
  int tid = threadIdx.x;
  long unit0 = (long)blockIdx.x * 16;
  int u = tid >> 4, l = tid & 15;
  const float* hid = hid_all + (unit0 + u) * 256;
  float p0 = 0.f, p1 = 0.f, p2 = 0.f;
  for (int k = l; k < 256; k += 16) {
    float h = hid[k];
    p0 = fmaf(h, w_pro[k],       p0);
    p1 = fmaf(h, w_pro[256 + k], p1);
    p2 = fmaf(h, w_pro[512 + k], p2);
  }
  #pragma unroll
  for (int off = 8; off; off >>= 1) {
    p0 += __shfl_down(p0, off, 16);
    p1 += __shfl_down(p1, off, 16);
    p2 += __shfl_down(p2, off, 16);
  }
  if (l == 0) {
    long unit = unit0 + u;
    zwb_all[unit*3+0] = fmaxf(p0 + b_pro[0], 0.f) + zwr_all[unit*3+0];
    zwb_all[unit*3+1] = fmaxf(p1 + b_pro[1], 0.f) + zwr_all[unit*3+1];
    zwb_all[unit*3+2] = fmaxf(p2 + b_pro[2], 0.f) + zwr_all[unit*3+2];
  }
}

// ------------------------------------------------------------- glimpse ----
DEV float bilin_sample(const float* im, int y, int x) {
  bool valid = ((unsigned)x < 50u) && ((unsigned)y < 50u);
  int yc = min(max(y, 0), 49), xc = min(max(x, 0), 49);
  float v = im[yc*50 + xc];
  return valid ? v : 0.f;
}

__global__ __launch_bounds__(256) void gfill_kernel(
    const float* __restrict__ img, const float* __restrict__ zwbp, int zstride,
    long ibase, int shift, float* __restrict__ g_out)
{
  __shared__ float zwb[16][3];
  int tid = threadIdx.x;
  long unit0 = (long)blockIdx.x * 16;
  if (tid < 48) {
    int u = tid / 3, j = tid - u*3;
    zwb[u][j] = zwbp[(unit0 + u)*(long)zstride + j];
  }
  __syncthreads();
  for (int p = tid; p < 16*400; p += 256) {
    int u = p / 400, pix = p - u*400;
    long item = (ibase + unit0 + u) >> shift;
    float s = zwb[u][0], tx = zwb[u][1], ty = zwb[u][2];
    int iyi = pix / 20, ixi = pix - iyi*20;
    float bx = (2.f*ixi + 1.f)/20.f - 1.f;
    float by = (2.f*iyi + 1.f)/20.f - 1.f;
    float x = s*bx + tx, y = s*by + ty;
    float ix = ((x + 1.f)*50.f - 1.f)*0.5f;
    float iy = ((y + 1.f)*50.f - 1.f)*0.5f;
    float x0f = floorf(ix), y0f = floorf(iy);
    float wx = ix - x0f, wy = iy - y0f;
    int x0 = (int)x0f, y0 = (int)y0f;
    const float* im = img + item*2500;
    float v00 = bilin_sample(im, y0,   x0  );
    float v01 = bilin_sample(im, y0,   x0+1);
    float v10 = bilin_sample(im, y0+1, x0  );
    float v11 = bilin_sample(im, y0+1, x0+1);
    g_out[(unit0+u)*400 + pix] = v00*(1.f-wx)*(1.f-wy) + v01*wx*(1.f-wy)
                               + v10*(1.f-wx)*wy       + v11*wx*wy;
  }
}

// --------------------------------------------------------------- GEMMs ----
// Big-gate GEMM, round-11 "gemmT": 256x32 tile, 256 threads, 4x8 micro,
// 2 wgs/CU. Wave w owns cols cw=8w (wave-uniform); lane l owns rows 4l..4l+3.
//   A: LDS As[2][16][256], 1 ds_read_b128 per k per lane (minimum), batched
//      4-deep per group (round-9 MLP lesson).
//   B: LDS Bs[2][16][32] (2KB tile, staged by threads 0..127, coalesced).
//      Read as TWO UNIFORM-ADDRESS b128 per k -> HW broadcast (m136: same-
//      address is conflict-free; ~16B unique data vs 1024B scattered).
//      This keeps B on the LDS pipe (round-10: any off-LDS B path loses to
//      latency) but at broadcast cost instead of gemmH's scattered reads.
// Live regs ~110 < 128 cap (round-8 spill lesson).
// Per-output order: fmaf ascending k, bias last -> bit-identical.
__global__ __launch_bounds__(256, 2) void gemmT_kernel(
    const float* __restrict__ A, int lda,
    const float* __restrict__ Wt, int ldwt,
    const float* __restrict__ bias,
    float* __restrict__ C, int ldc, int K)
{
  __shared__ float As[2][16][256];
  __shared__ float Bs[2][16][32];
  int tid  = threadIdx.x;
  int lane = tid & 63;
  int m0 = blockIdx.x << 8;           // 256-row tile
  int n0 = blockIdx.y << 5;           // 32-col tile
  int cw = (tid >> 6) << 3;           // wave's col offset: 0,8,16,24 (uniform)
  const float* Ap = A + (long)(m0 + tid)*lda;   // this thread's A row
  int bk = tid >> 3, bn = (tid & 7) << 2;       // B staging map (tid<128)
  const float* Bp = Wt + (long)bk*ldwt + n0 + bn;
  float acc[4][8] = {};

  // prologue: tile 0 -> LDS buf 0
  float4 pa0 = *(const float4*)(Ap + 0);
  float4 pa1 = *(const float4*)(Ap + 4);
  float4 pa2 = *(const float4*)(Ap + 8);
  float4 pa3 = *(const float4*)(Ap + 12);
  float4 pb = (tid < 128) ? *(const float4*)(Bp) : make_float4(0.f,0.f,0.f,0.f);
  As[0][ 0][tid]=pa0.x; As[0][ 1][tid]=pa0.y; As[0][ 2][tid]=pa0.z; As[0][ 3][tid]=pa0.w;
  As[0][ 4][tid]=pa1.x; As[0][ 5][tid]=pa1.y; As[0][ 6][tid]=pa1.z; As[0][ 7][tid]=pa1.w;
  As[0][ 8][tid]=pa2.x; As[0][ 9][tid]=pa2.y; As[0][10][tid]=pa2.z; As[0][11][tid]=pa2.w;
  As[0][12][tid]=pa3.x; As[0][13][tid]=pa3.y; As[0][14][tid]=pa3.z; As[0][15][tid]=pa3.w;
  if (tid < 128) *(float4*)&Bs[0][bk][bn] = pb;
  __syncthreads();

  int buf = 0;
  for (int k0 = 16;; k0 += 16) {
    bool more = k0 < K;
    if (more) {
      pa0 = *(const float4*)(Ap + k0);
      pa1 = *(const float4*)(Ap + k0 + 4);
      pa2 = *(const float4*)(Ap + k0 + 8);
      pa3 = *(const float4*)(Ap + k0 + 12);
      if (tid < 128) pb = *(const float4*)(Bp + (long)k0*ldwt);
    }
    #pragma unroll
    for (int g = 0; g < 4; g++) {
      // 4 scattered A reads + 8 broadcast B reads issued together (MLP)
      float4 av0 = *(const float4*)&As[buf][g*4+0][lane << 2];
      float4 av1 = *(const float4*)&As[buf][g*4+1][lane << 2];
      float4 av2 = *(const float4*)&As[buf][g*4+2][lane << 2];
      float4 av3 = *(const float4*)&As[buf][g*4+3][lane << 2];
      float4 bv00 = *(const float4*)&Bs[buf][g*4+0][cw];
      float4 bv01 = *(const float4*)&Bs[buf][g*4+0][cw+4];
      float4 bv10 = *(const float4*)&Bs[buf][g*4+1][cw];
      float4 bv11 = *(const float4*)&Bs[buf][g*4+1][cw+4];
      float4 bv20 = *(const float4*)&Bs[buf][g*4+2][cw];
      float4 bv21 = *(const float4*)&Bs[buf][g*4+2][cw+4];
      float4 bv30 = *(const float4*)&Bs[buf][g*4+3][cw];
      float4 bv31 = *(const float4*)&Bs[buf][g*4+3][cw+4];
      float a0[4] = {av0.x,av0.y,av0.z,av0.w};
      float a1[4] = {av1.x,av1.y,av1.z,av1.w};
      float a2[4] = {av2.x,av2.y,av2.z,av2.w};
      float a3[4] = {av3.x,av3.y,av3.z,av3.w};
      float b0[8] = {bv00.x,bv00.y,bv00.z,bv00.w, bv01.x,bv01.y,bv01.z,bv01.w};
      float b1[8] = {bv10.x,bv10.y,bv10.z,bv10.w, bv11.x,bv11.y,bv11.z,bv11.w};
      float b2[8] = {bv20.x,bv20.y,bv20.z,bv20.w, bv21.x,bv21.y,bv21.z,bv21.w};
      float b3[8] = {bv30.x,bv30.y,bv30.z,bv30.w, bv31.x,bv31.y,bv31.z,bv31.w};
      #pragma unroll
      for (int j = 0; j < 8; j++) {
        #pragma unroll
        for (int i = 0; i < 4; i++) {
          // k ascending per output: g*4+0, +1, +2, +3
          acc[i][j] = fmaf(a0[i], b0[j], acc[i][j]);
          acc[i][j] = fmaf(a1[i], b1[j], acc[i][j]);
          acc[i][j] = fmaf(a2[i], b2[j], acc[i][j]);
          acc[i][j] = fmaf(a3[i], b3[j], acc[i][j]);
        }
      }
    }
    if (!more) break;
    buf ^= 1;
    As[buf][ 0][tid]=pa0.x; As[buf][ 1][tid]=pa0.y; As[buf][ 2][tid]=pa0.z; As[buf][ 3][tid]=pa0.w;
    As[buf][ 4][tid]=pa1.x; As[buf][ 5][tid]=pa1.y; As[buf][ 6][tid]=pa1.z; As[buf][ 7][tid]=pa1.w;
    As[buf][ 8][tid]=pa2.x; As[buf][ 9][tid]=pa2.y; As[buf][10][tid]=pa2.z; As[buf][11][tid]=pa2.w;
    As[buf][12][tid]=pa3.x; As[buf][13][tid]=pa3.y; As[buf][14][tid]=pa3.z; As[buf][15][tid]=pa3.w;
    if (tid < 128) *(float4*)&Bs[buf][bk][bn] = pb;
    __syncthreads();
  }

  float bj[8];
  #pragma unroll
  for (int j = 0; j < 8; j++) bj[j] = bias[n0 + cw + j];
  #pragma unroll
  for (int i = 0; i < 4; i++) {
    int mi = m0 + (lane << 2) + i;
    float* Crow = C + (long)mi*ldc + n0 + cw;
    float4 v0 = make_float4(acc[i][0]+bj[0], acc[i][1]+bj[1],
                            acc[i][2]+bj[2], acc[i][3]+bj[3]);
    float4 v1 = make_float4(acc[i][4]+bj[4], acc[i][5]+bj[5],
                            acc[i][6]+bj[6], acc[i][7]+bj[7]);
    *(float4*)(Crow)     = v0;
    *(float4*)(Crow + 4) = v1;
  }
}

// 64x64 tile, 4x4 micro, N-bounded, optional ReLU. K % 16 == 0 REQUIRED.
template<bool RELU>
__global__ __launch_bounds__(256) void gemmNK64_kernel(
    const float* __restrict__ A, int lda,
    const float* __restrict__ W, int ldw,
    const float* __restrict__ bias,
    float* __restrict__ C, int ldc, int K, int N)
{
  __shared__ float As[16][68];
  __shared__ float Bs[16][68];
  int tid = threadIdx.x;
  int m0 = blockIdx.x << 6, n0 = blockIdx.y << 6;
  int r  = tid >> 2;
  int kq = (tid & 3) << 2;
  const float* Ap = A + (long)(m0 + r)*lda + kq;
  const float* Wp = W + (long)(n0 + r)*ldw + kq;
  bool wv = (n0 + r) < N;
  int tm = (tid & 15) << 2;
  int tn = ((tid >> 4) & 15) << 2;
  float acc[4][4] = {};
  float4 a0 = *(const float4*)Ap;
  float4 b0 = wv ? *(const float4*)Wp : make_float4(0.f,0.f,0.f,0.f);
  for (int k0 = 16;; k0 += 16) {
    __syncthreads();
    As[kq+0][r]=a0.x; As[kq+1][r]=a0.y; As[kq+2][r]=a0.z; As[kq+3][r]=a0.w;
    Bs[kq+0][r]=b0.x; Bs[kq+1][r]=b0.y; Bs[kq+2][r]=b0.z; Bs[kq+3][r]=b0.w;
    __syncthreads();
    if (k0 < K) {
      a0 = *(const float4*)(Ap + k0);
      b0 = wv ? *(const float4*)(Wp + k0) : make_float4(0.f,0.f,0.f,0.f);
    }
    #pragma unroll
    for (int k = 0; k < 16; k++) {
      float4 av = *(const float4*)&As[k][tm];
      float4 bv = *(const float4*)&Bs[k][tn];
      float a[4] = {av.x,av.y,av.z,av.w};
      float b[4] = {bv.x,bv.y,bv.z,bv.w};
      #pragma unroll
      for (int i = 0; i < 4; i++)
        #pragma unroll
        for (int j = 0; j < 4; j++)
          acc[i][j] = fmaf(a[i], b[j], acc[i][j]);
    }
    if (k0 >= K) break;
  }
  #pragma unroll
  for (int i = 0; i < 4; i++) {
    int mi = m0 + tm + i;
    float* Crow = C + (long)mi*ldc + n0;
    #pragma unroll
    for (int j = 0; j < 4; j++) {
      int nj = tn + j;
      if (n0 + nj < N) {
        float v = acc[i][j] + bias[n0 + nj];
        if (RELU) v = fmaxf(v, 0.f);
        Crow[nj] = v;
      }
    }
  }
}

// ------------------------------------------------------------ assemble ----
__global__ void assemble_kernel(
    const float* __restrict__ enc_all, const float* __restrict__ zwhat_lt,
    const float* __restrict__ zwhere_lt, const float* __restrict__ hid_lt, int t,
    float* __restrict__ x_rel, float* __restrict__ x_tem, float* __restrict__ x_mt)
{
  long idx = (long)blockIdx.x * 256 + threadIdx.x;
  const int PER = 715;
  long item = idx / PER;
  int c = (int)(idx - item*PER);
  if (item >= NB) return;
  long ut = item*16 + t;
  if (c < 100)      x_rel[item*KREL + c]             = enc_all[ut*100 + c];
  else if (c < 103) x_rel[item*KREL + 100 + (c-100)] = zwhere_lt[ut*3 + (c-100)];
  else if (c < 153) x_rel[item*KREL + 106 + (c-103)] = zwhat_lt[ut*50 + (c-103)];
  else if (c < 409) x_rel[item*KREL + 206 + (c-153)] = hid_lt[ut*256 + (c-153)];
  else if (c < 665) x_tem[item*KTEM + 103 + (c-409)] = hid_lt[ut*256 + (c-409)];
  else              x_mt [item*KMT  + (c-665)]       = zwhat_lt[ut*50 + (c-665)];
}

// ----------------------------------------------------------- pointwise ----
// rel LSTM + m_where/s_where/z_where_i (serial chains, round-3 order)
__global__ __launch_bounds__(256) void lstm_rel_kernel(
    const float* __restrict__ gates,
    float* __restrict__ h_rela, float* __restrict__ c_rela,
    float* __restrict__ x_rel, float* __restrict__ x_tem, float* __restrict__ x_mt,
    const float* __restrict__ zwhere_lt, const float* __restrict__ w_lwhere,
    const float* __restrict__ b_lwhere, const float* __restrict__ eps_where, int t,
    float* __restrict__ m_where, float* __restrict__ s_where,
    float* __restrict__ o_zwhere)
{
  __shared__ float sh[256];
  long item = blockIdx.x;
  int j = threadIdx.x;
  const float* grow = gates + item*1024;
  float ig = grow[j], fg = grow[256+j], gg = grow[512+j], og = grow[768+j];
  long hi = item*256 + j;
  float c  = c_rela[hi];
  float c2 = sigm(fg)*c + sigm(ig)*tanhf(gg);
  float h2 = sigm(og)*tanhf(c2);
  c_rela[hi] = c2;
  h_rela[hi] = h2;
  sh[j] = h2;
  x_tem[item*KTEM + 359 + j] = h2;
  x_tem[item*KTEM + 615 + j] = h2;
  x_mt [item*KMT  +  50 + j] = h2;
  x_rel[item*KREL + 462 + j] = h2;   // for step t+1
  __syncthreads();
  if (j < 3) {
    long ut = item*16 + t;
    const float* wm  = w_lwhere + j*259;
    const float* wsr = w_lwhere + (j+3)*259;
    float am = b_lwhere[j], as = b_lwhere[j+3];
    #pragma unroll
    for (int k = 0; k < 3; k++) {
      float v = zwhere_lt[ut*3 + k];
      am = fmaf(v, wm[k], am);  as = fmaf(v, wsr[k], as);
    }
    for (int k = 0; k < 256; k++) {
      float v = sh[k];
      am = fmaf(v, wm[3+k], am);  as = fmaf(v, wsr[3+k], as);
    }
    float s = softp(as) + 1e-4f;
    float zw = am + s * eps_where[ut*3 + j];
    m_where[item*3 + j] = am;
    s_where[item*3 + j] = s;
    o_zwhere[ut*3 + j]  = zw;
    x_rel[item*KREL + 103 + j] = zw;   // zw_prev for step t+1
  }
}

__global__ void lstm_tem_kernel(const float* __restrict__ gates,
    const float* __restrict__ c_rela, float* __restrict__ o_htemp, int t,
    float* __restrict__ x_mt, float* __restrict__ x_tem,
    const float* __restrict__ o_zwhere)
{
  long idx = (long)blockIdx.x * 256 + threadIdx.x;
  if (idx >= (long)NB*256) return;
  long item = idx >> 8; int j = (int)(idx & 255);
  const float* grow = gates + item*1024;
  float ig = grow[j], fg = grow[256+j], gg = grow[512+j], og = grow[768+j];
  float c  = c_rela[idx];
  float c2 = sigm(fg)*c + sigm(ig)*tanhf(gg);
  float h2 = sigm(og)*tanhf(c2);
  long ut = item*16 + t;
  o_htemp[ut*256 + j] = h2;
  x_mt[item*KMT + 306 + j] = h2;
  if (j < 3) x_tem[item*KTEM + 100 + j] = o_zwhere[ut*3 + j];  // zw_prev for t+1
}

// pres + z_what sampling fused (z_what values identical to round-3 zwhat_kernel)
__global__ __launch_bounds__(256) void pres_kernel(
    const float* __restrict__ o_zwhere,
    const float* __restrict__ h_rela, const float* __restrict__ o_htemp,
    const float* __restrict__ w_lpres, const float* __restrict__ b_lpres,
    const float* __restrict__ zpres_lt, const float* __restrict__ u_pres, int t,
    const float* __restrict__ mt, const float* __restrict__ m_where,
    const float* __restrict__ s_where, const float* __restrict__ eps_what,
    float* __restrict__ o_zwhat, float* __restrict__ x_rel,
    float* __restrict__ o_zpres, float* __restrict__ out_klwhat,
    float* __restrict__ out_klwhere)
{
  int tid = threadIdx.x;
  long item = (long)blockIdx.x*4 + (tid >> 6);
  if (item >= NB) return;
  int l = tid & 63;
  long ut = item*16 + t;
  float part = 0.f;
  for (int c = l; c < 565; c += 64) {
    float x;
    if (c < 50) {
      float m = mt[item*100 + c];
      float s = softp(mt[item*100 + 50 + c]) + 1e-4f;
      x = m + s * eps_what[ut*50 + c];
      o_zwhat[ut*50 + c] = x;
      x_rel[item*KREL + 156 + c] = x;   // zwt_prev for step t+1
    }
    else if (c < 53)  x = o_zwhere[ut*3 + (c-50)];
    else if (c < 309) x = h_rela[item*256 + (c-53)];
    else              x = o_htemp[ut*256 + (c-309)];
    part = fmaf(x, w_lpres[c], part);
  }
  #pragma unroll
  for (int off = 32; off; off >>= 1) part += __shfl_down(part, off);
  float zpres = 0.f;
  if (l == 0) {
    float p = sigm(part + b_lpres[0]);
    zpres = (u_pres[ut] < p * zpres_lt[ut]) ? 1.f : 0.f;
    o_zpres[ut] = zpres;
  }
  float w = __shfl(zpres, 0);
  float kw = 0.f, kwh = 0.f;
  if (l < 50) {
    float m = mt[item*100 + l];
    float s = softp(mt[item*100 + 50 + l]) + 1e-4f;
    kw = -logf(s) + 0.5f*(s*s + m*m) - 0.5f;
  }
  if (l < 3) {
    float m = m_where[item*3 + l], s = s_where[item*3 + l];
    float m0 = (l == 0) ? 0.3f : 0.f;
    float s0 = (l == 0) ? 0.1f : 1.f;
    kwh = logf(s0 / s) + (s*s + (m-m0)*(m-m0)) / (2.f*s0*s0) - 0.5f;
  }
  #pragma unroll
  for (int off = 32; off; off >>= 1) {
    kw  += __shfl_down(kw,  off);
    kwh += __shfl_down(kwh, off);
  }
  if (l == 0) {
    out_klwhat[item]  += w * kw;
    out_klwhere[item] += w * kwh;
  }
}

// ---------------------------------------------------------------- host ----
extern "C" void kernel_launch(void* const* d_in, const int* in_sizes, int n_in,
                              void* d_out, int out_size, void* d_ws, size_t ws_size,
                              hipStream_t stream) {
  (void)in_sizes; (void)n_in; (void)out_size; (void)ws_size;
  const float* img       = (const float*)d_in[0];
  const float* zwhat_lt  = (const float*)d_in[1];
  const float* zwhere_lt = (const float*)d_in[2];
  const float* zpres_lt  = (const float*)d_in[3];
  const float* hid_lt    = (const float*)d_in[4];
  const float* eps_where = (const float*)d_in[5];
  const float* eps_what  = (const float*)d_in[6];
  const float* u_pres    = (const float*)d_in[7];
  const float* w_pro     = (const float*)d_in[8];
  const float* b_pro     = (const float*)d_in[9];
  const float* w_ge1     = (const float*)d_in[10];
  const float* b_ge1     = (const float*)d_in[11];
  const float* w_ge2     = (const float*)d_in[12];
  const float* b_ge2     = (const float*)d_in[13];
  const float* wih_rel   = (const float*)d_in[14];
  const float* whh_rel   = (const float*)d_in[15];
  const float* bih_rel   = (const float*)d_in[16];
  const float* bhh_rel   = (const float*)d_in[17];
  const float* wih_tem   = (const float*)d_in[18];
  const float* whh_tem   = (const float*)d_in[19];
  const float* bih_tem   = (const float*)d_in[20];
  const float* bhh_tem   = (const float*)d_in[21];
  const float* w_lwhere  = (const float*)d_in[22];
  const float* b_lwhere  = (const float*)d_in[23];
  const float* w_lwhat   = (const float*)d_in[24];
  const float* b_lwhat   = (const float*)d_in[25];
  const float* w_lpres   = (const float*)d_in[26];
  const float* b_lpres   = (const float*)d_in[27];

  float* ws = (float*)d_ws;
  float* W_relT   = ws;                       // 737280  (720 x 1024, k-major)
  float* W_temT   = W_relT + 737280;          // 901120  (880 x 1024, k-major)
  float* W_mt     = W_temT + 901120;          // 57600
  float* W_ge2p   = W_mt + 57600;             // 20800
  float* bias_rel = W_ge2p + 20800;           // 1024
  float* bias_tem = bias_rel + 1024;          // 1024
  float* zwb_all  = bias_tem + 1024;          // 196608
  float* enc_all  = zwb_all + 196608;         // 6553600
  float* g_buf    = enc_all + 6553600;        // 6553600 (CH*400)
  float* h1_buf   = g_buf + 6553600;          // 3407872 (CH*208)
  float* x_rel    = h1_buf + 3407872;         // 2949120
  float* x_tem    = x_rel + 2949120;          // 3604480
  float* x_mt     = x_tem + 3604480;          // 2359296
  float* gates    = x_mt + 2359296;           // 4194304
  float* h_rela   = gates + 4194304;          // 1048576
  float* c_rela   = h_rela + 1048576;         // 1048576
  float* m_where  = c_rela + 1048576;         // 12288
  float* s_where  = m_where + 12288;          // 12288
  float* mtbuf    = s_where + 12288;          // 409600

  float* out       = (float*)d_out;
  float* o_zwhat   = out + OUT_ZWHAT;
  float* o_zwhere  = out + OUT_ZWHERE;
  float* o_zpres   = out + OUT_ZPRES;
  float* o_klwhat  = out + OUT_KLWHAT;
  float* o_htemp   = out + OUT_HTEMP;

  prep_kernel<<<63067, 256, 0, stream>>>(wih_rel, whh_rel, bih_rel, bhh_rel,
      wih_tem, whh_tem, bih_tem, bhh_tem, w_lwhat, w_ge2,
      W_relT, W_temT, W_mt, W_ge2p, bias_rel, bias_tem, h_rela, c_rela,
      x_rel, x_tem, x_mt, h1_buf, o_klwhat);

  zwb_kernel<<<4096, 256, 0, stream>>>(hid_lt, zwhere_lt, w_pro, b_pro, zwb_all);

  for (int c = 0; c < 4; c++) {
    gfill_kernel<<<CH/16, 256, 0, stream>>>(img, zwb_all + (long)c*CH*3, 3,
        (long)c*CH, 4, g_buf);
    gemmNK64_kernel<true><<<dim3(CH/64, 4), 256, 0, stream>>>(
        g_buf, 400, w_ge1, 400, b_ge1, h1_buf, KGE2, 400, 200);
    gemmNK64_kernel<false><<<dim3(CH/64, 2), 256, 0, stream>>>(
        h1_buf, KGE2, W_ge2p, KGE2, b_ge2, enc_all + (long)c*CH*100, 100, KGE2, 100);
  }

  for (int t = 0; t < TT; t++) {
    assemble_kernel<<<11440, 256, 0, stream>>>(enc_all, zwhat_lt, zwhere_lt,
        hid_lt, t, x_rel, x_tem, x_mt);
    gemmT_kernel<<<dim3(16, 32), 256, 0, stream>>>(x_rel, KREL, W_relT, NG,
        bias_rel, gates, NG, KREL);
    lstm_rel_kernel<<<4096, 256, 0, stream>>>(gates, h_rela, c_rela,
        x_rel, x_tem, x_mt, zwhere_lt, w_lwhere, b_lwhere, eps_where, t,
        m_where, s_where, o_zwhere);
    gfill_kernel<<<256, 256, 0, stream>>>(img, o_zwhere + t*3, 48, 0, 0, g_buf);
    gemmNK64_kernel<true><<<dim3(64, 4), 256, 0, stream>>>(
        g_buf, 400, w_ge1, 400, b_ge1, h1_buf, KGE2, 400, 200);
    gemmNK64_kernel<false><<<dim3(64, 2), 256, 0, stream>>>(
        h1_buf, KGE2, W_ge2p, KGE2, b_ge2, x_tem, KTEM, KGE2, 100);
    gemmT_kernel<<<dim3(16, 32), 256, 0, stream>>>(x_tem, KTEM, W_temT, NG,
        bias_tem, gates, NG, KTEM);
    lstm_tem_kernel<<<4096, 256, 0, stream>>>(gates, c_rela, o_htemp, t,
        x_mt, x_tem, o_zwhere);
    gemmNK64_kernel<false><<<dim3(64, 2), 256, 0, stream>>>(
        x_mt, KMT, W_mt, KMT, b_lwhat, mtbuf, 100, KMT, 100);
    pres_kernel<<<1024, 256, 0, stream>>>(o_zwhere, h_rela, o_htemp,
        w_lpres, b_lpres, zpres_lt, u_pres, t, mtbuf, m_where, s_where,
        eps_what, o_zwhat, x_rel, o_zpres, o_klwhat, o_klwhat + 4096);
  }
}

// Round 10
// 5477.476 us; speedup vs baseline: 5.1735x; 1.0547x over previous
//
#include <hip/hip_runtime.h>
#include <math.h>

#define DEV __device__ __forceinline__

// NUMERICS FREEZE: every output element keeps round-1's exact fp order:
// one thread per output, fmaf ascending over k, bias added once at the end.
// Only order-preserving optimizations (tiling/occupancy/fusion) allowed.
// Round-2 lesson: any reorder flips a u < p*zp threshold somewhere -> FAIL.
// GEMM exploration (rounds 6-11) converged: under the freeze,
// outputs/thread x waves = 4M/64 fixed; >=2 waves/SIMD needed (1/SIMD
// exposes latency: 112->160us) => <=32 out/thread => LDS >=1.5B/fma
// => ~105us/dispatch floor. gemmH (8x4 micro, 128x64 tile, A+B in LDS)
// measures 107us = floor+2%. Failed alternatives: 64-VGPR B buffer ->
// spill (898us); v_readlane B -> VALU tax (137us); s_load B -> L2 miss
// ~900cyc (129us); broadcast-B LDS -> same issue slots (117us).
// This round: revert to gemmH; fuse t-loop gfill into lstm_rel (-16
// launches); zero-init via 3 hipMemsetAsync (prep 63067 -> 6715 blocks).

constexpr int NB    = 4096;
constexpr int TT    = 16;
constexpr int KREL  = 720;   // [enc 100 | zwr 3 | zw_prev 3 | zwt_l 50 | zwt_prev 50 | hid 256 | h 256 | pad 2]
constexpr int KTEM  = 880;   // [enc 100 | zw_prev 3 | hid 256 | h 256 | h(whh) 256 | pad 9]
constexpr int KMT   = 576;   // [zwt_l 50 | h_rela 256 | h_temp 256 | pad 14]
constexpr int KGE2  = 208;   // 200 padded
constexpr int NG    = 1024;
constexpr int CH    = 16384; // enc chunk units

constexpr long OUT_ZWHAT   = 0L;
constexpr long OUT_ZWHERE  = 3276800L;
constexpr long OUT_ZPRES   = 3473408L;
constexpr long OUT_KLWHAT  = 3538944L;
constexpr long OUT_HTEMP   = 3547136L;

DEV float sigm(float x)  { return 1.f / (1.f + expf(-x)); }
DEV float softp(float x) { return fmaxf(x, 0.f) + log1pf(expf(-fabsf(x))); }

// ---------------------------------------------------------------- prep ----
// W_relT/W_temT are k-major (transposed): W*T[k][n], n contiguous.
// Zero-init segments moved to hipMemsetAsync in kernel_launch.
__global__ void prep_kernel(
    const float* __restrict__ wih_rel, const float* __restrict__ whh_rel,
    const float* __restrict__ bih_rel, const float* __restrict__ bhh_rel,
    const float* __restrict__ wih_tem, const float* __restrict__ whh_tem,
    const float* __restrict__ bih_tem, const float* __restrict__ bhh_tem,
    const float* __restrict__ w_lwhat, const float* __restrict__ w_ge2,
    float* __restrict__ W_relT, float* __restrict__ W_temT, float* __restrict__ W_mt,
    float* __restrict__ W_ge2p,
    float* __restrict__ bias_rel, float* __restrict__ bias_tem)
{
  long idx = (long)blockIdx.x * 256 + threadIdx.x;
  if (idx < 737280) { int k = (int)(idx >> 10), j = (int)(idx & 1023);
    W_relT[idx] = (k < 462) ? wih_rel[j*462+k] : (k < 718 ? whh_rel[j*256 + (k-462)] : 0.f); return; }
  idx -= 737280;
  if (idx < 901120) { int k = (int)(idx >> 10), j = (int)(idx & 1023);
    W_temT[idx] = (k < 615) ? wih_tem[j*615+k] : (k < 871 ? whh_tem[j*256 + (k-615)] : 0.f); return; }
  idx -= 901120;
  if (idx < 57600) { int j = (int)(idx/576), k = (int)(idx - (long)j*576);
    W_mt[idx] = (k < 562) ? w_lwhat[j*562+k] : 0.f; return; }
  idx -= 57600;
  if (idx < 20800) { int j = (int)(idx/208), k = (int)(idx - (long)j*208);
    W_ge2p[idx] = (k < 200) ? w_ge2[j*200+k] : 0.f; return; }
  idx -= 20800;
  if (idx < 1024) { bias_rel[idx] = bih_rel[idx] + bhh_rel[idx]; return; }
  idx -= 1024;
  if (idx < 1024) { bias_tem[idx] = bih_tem[idx] + bhh_tem[idx]; return; }
}

// z_where_bias for all 65536 units (round-1 reduction order)
__global__ __launch_bounds__(256) void zwb_kernel(
    const float* __restrict__ hid_all, const float* __restrict__ zwr_all,
    const float* __restrict__ w_pro, const float* __restrict__ b_pro,
    float* __restrict__ zwb_all)
{
  int tid = threadIdx.x;
  long unit0 = (long)blockIdx.x * 16;
  int u = tid >> 4, l = tid & 15;
  const float* hid = hid_all + (unit0 + u) * 256;
  float p0 = 0.f, p1 = 0.f, p2 = 0.f;
  for (int k = l; k < 256; k += 16) {
    float h = hid[k];
    p0 = fmaf(h, w_pro[k],       p0);
    p1 = fmaf(h, w_pro[256 + k], p1);
    p2 = fmaf(h, w_pro[512 + k], p2);
  }
  #pragma unroll
  for (int off = 8; off; off >>= 1) {
    p0 += __shfl_down(p0, off, 16);
    p1 += __shfl_down(p1, off, 16);
    p2 += __shfl_down(p2, off, 16);
  }
  if (l == 0) {
    long unit = unit0 + u;
    zwb_all[unit*3+0] = fmaxf(p0 + b_pro[0], 0.f) + zwr_all[unit*3+0];
    zwb_all[unit*3+1] = fmaxf(p1 + b_pro[1], 0.f) + zwr_all[unit*3+1];
    zwb_all[unit*3+2] = fmaxf(p2 + b_pro[2], 0.f) + zwr_all[unit*3+2];
  }
}

// ------------------------------------------------------------- glimpse ----
DEV float bilin_sample(const float* im, int y, int x) {
  bool valid = ((unsigned)x < 50u) && ((unsigned)y < 50u);
  int yc = min(max(y, 0), 49), xc = min(max(x, 0), 49);
  float v = im[yc*50 + xc];
  return valid ? v : 0.f;
}

DEV float glimpse_px(const float* im, float s, float tx, float ty, int pix) {
  int iyi = pix / 20, ixi = pix - iyi*20;
  float bx = (2.f*ixi + 1.f)/20.f - 1.f;
  float by = (2.f*iyi + 1.f)/20.f - 1.f;
  float x = s*bx + tx, y = s*by + ty;
  float ix = ((x + 1.f)*50.f - 1.f)*0.5f;
  float iy = ((y + 1.f)*50.f - 1.f)*0.5f;
  float x0f = floorf(ix), y0f = floorf(iy);
  float wx = ix - x0f, wy = iy - y0f;
  int x0 = (int)x0f, y0 = (int)y0f;
  float v00 = bilin_sample(im, y0,   x0  );
  float v01 = bilin_sample(im, y0,   x0+1);
  float v10 = bilin_sample(im, y0+1, x0  );
  float v11 = bilin_sample(im, y0+1, x0+1);
  return v00*(1.f-wx)*(1.f-wy) + v01*wx*(1.f-wy)
       + v10*(1.f-wx)*wy       + v11*wx*wy;
}

__global__ __launch_bounds__(256) void gfill_kernel(
    const float* __restrict__ img, const float* __restrict__ zwbp, int zstride,
    long ibase, int shift, float* __restrict__ g_out)
{
  __shared__ float zwb[16][3];
  int tid = threadIdx.x;
  long unit0 = (long)blockIdx.x * 16;
  if (tid < 48) {
    int u = tid / 3, j = tid - u*3;
    zwb[u][j] = zwbp[(unit0 + u)*(long)zstride + j];
  }
  __syncthreads();
  for (int p = tid; p < 16*400; p += 256) {
    int u = p / 400, pix = p - u*400;
    long item = (ibase + unit0 + u) >> shift;
    const float* im = img + item*2500;
    g_out[(unit0+u)*400 + pix] =
        glimpse_px(im, zwb[u][0], zwb[u][1], zwb[u][2], pix);
  }
}

// --------------------------------------------------------------- GEMMs ----
// Big-gate GEMM "gemmH" (round-3 verified, 107us): 128x64 tile, 256 threads,
// 8x4 micro, double-buffered LDS, 2 wgs/CU = 2 waves/SIMD. This sits at the
// order-preserving structural floor (see header comment).
// Per-output order unchanged: fmaf ascending k, bias last (bit-identical).
// Thread owns rows {tm+0..3, tm+64..67} x cols {tn+0..3}.
__global__ __launch_bounds__(256, 2) void gemmH_kernel(
    const float* __restrict__ A, int lda,
    const float* __restrict__ Wt, int ldwt,
    const float* __restrict__ bias,
    float* __restrict__ C, int ldc, int K)
{
  __shared__ float As[2][16][132];
  __shared__ float Bs[2][16][68];
  int tid = threadIdx.x;
  int m0 = blockIdx.x << 7, n0 = blockIdx.y << 6;
  // A staging: thread -> row m0+ar, k-cols ak..ak+7 (2-way write alias, free)
  int ar = tid >> 1, ak = (tid & 1) << 3;
  const float* Ap = A + (long)(m0 + ar)*lda + ak;
  // B staging: thread -> k-row bk, n-cols bn..bn+3
  int bk = tid >> 4, bn = (tid & 15) << 2;
  const float* Bp = Wt + (long)bk*ldwt + n0 + bn;
  // compute fragment offsets
  int tm = (tid & 15) << 2;          // 0,4,...,60  (row group; +0 / +64)
  int tn = ((tid >> 4) & 15) << 2;   // 0,4,...,60  (col group)
  float acc[8][4] = {};
  float4 a0 = *(const float4*)(Ap);
  float4 a1 = *(const float4*)(Ap + 4);
  float4 b0 = *(const float4*)(Bp);
  As[0][ak+0][ar] = a0.x; As[0][ak+1][ar] = a0.y;
  As[0][ak+2][ar] = a0.z; As[0][ak+3][ar] = a0.w;
  As[0][ak+4][ar] = a1.x; As[0][ak+5][ar] = a1.y;
  As[0][ak+6][ar] = a1.z; As[0][ak+7][ar] = a1.w;
  *(float4*)&Bs[0][bk][bn] = b0;
  __syncthreads();
  int buf = 0;
  for (int k0 = 16;; k0 += 16) {
    bool more = k0 < K;
    if (more) {
      a0 = *(const float4*)(Ap + k0);
      a1 = *(const float4*)(Ap + k0 + 4);
      b0 = *(const float4*)(Bp + (long)k0*ldwt);
    }
    #pragma unroll
    for (int k = 0; k < 16; k++) {
      float4 av0 = *(const float4*)&As[buf][k][tm];
      float4 av1 = *(const float4*)&As[buf][k][tm+64];
      float4 bv  = *(const float4*)&Bs[buf][k][tn];
      float a[8] = {av0.x,av0.y,av0.z,av0.w,av1.x,av1.y,av1.z,av1.w};
      float b[4] = {bv.x,bv.y,bv.z,bv.w};
      #pragma unroll
      for (int i = 0; i < 8; i++)
        #pragma unroll
        for (int j = 0; j < 4; j++)
          acc[i][j] = fmaf(a[i], b[j], acc[i][j]);
    }
    if (!more) break;
    buf ^= 1;
    As[buf][ak+0][ar] = a0.x; As[buf][ak+1][ar] = a0.y;
    As[buf][ak+2][ar] = a0.z; As[buf][ak+3][ar] = a0.w;
    As[buf][ak+4][ar] = a1.x; As[buf][ak+5][ar] = a1.y;
    As[buf][ak+6][ar] = a1.z; As[buf][ak+7][ar] = a1.w;
    *(float4*)&Bs[buf][bk][bn] = b0;
    __syncthreads();
  }
  float bj[4];
  #pragma unroll
  for (int j = 0; j < 4; j++) bj[j] = bias[n0 + tn + j];
  #pragma unroll
  for (int i = 0; i < 8; i++) {
    int mi = m0 + tm + (i & 3) + ((i >> 2) << 6);
    float* Crow = C + (long)mi*ldc + n0;
    float4 v = make_float4(acc[i][0]+bj[0], acc[i][1]+bj[1],
                           acc[i][2]+bj[2], acc[i][3]+bj[3]);
    *(float4*)(Crow + tn) = v;
  }
}

// 64x64 tile, 4x4 micro, N-bounded, optional ReLU. K % 16 == 0 REQUIRED.
template<bool RELU>
__global__ __launch_bounds__(256) void gemmNK64_kernel(
    const float* __restrict__ A, int lda,
    const float* __restrict__ W, int ldw,
    const float* __restrict__ bias,
    float* __restrict__ C, int ldc, int K, int N)
{
  __shared__ float As[16][68];
  __shared__ float Bs[16][68];
  int tid = threadIdx.x;
  int m0 = blockIdx.x << 6, n0 = blockIdx.y << 6;
  int r  = tid >> 2;
  int kq = (tid & 3) << 2;
  const float* Ap = A + (long)(m0 + r)*lda + kq;
  const float* Wp = W + (long)(n0 + r)*ldw + kq;
  bool wv = (n0 + r) < N;
  int tm = (tid & 15) << 2;
  int tn = ((tid >> 4) & 15) << 2;
  float acc[4][4] = {};
  float4 a0 = *(const float4*)Ap;
  float4 b0 = wv ? *(const float4*)Wp : make_float4(0.f,0.f,0.f,0.f);
  for (int k0 = 16;; k0 += 16) {
    __syncthreads();
    As[kq+0][r]=a0.x; As[kq+1][r]=a0.y; As[kq+2][r]=a0.z; As[kq+3][r]=a0.w;
    Bs[kq+0][r]=b0.x; Bs[kq+1][r]=b0.y; Bs[kq+2][r]=b0.z; Bs[kq+3][r]=b0.w;
    __syncthreads();
    if (k0 < K) {
      a0 = *(const float4*)(Ap + k0);
      b0 = wv ? *(const float4*)(Wp + k0) : make_float4(0.f,0.f,0.f,0.f);
    }
    #pragma unroll
    for (int k = 0; k < 16; k++) {
      float4 av = *(const float4*)&As[k][tm];
      float4 bv = *(const float4*)&Bs[k][tn];
      float a[4] = {av.x,av.y,av.z,av.w};
      float b[4] = {bv.x,bv.y,bv.z,bv.w};
      #pragma unroll
      for (int i = 0; i < 4; i++)
        #pragma unroll
        for (int j = 0; j < 4; j++)
          acc[i][j] = fmaf(a[i], b[j], acc[i][j]);
    }
    if (k0 >= K) break;
  }
  #pragma unroll
  for (int i = 0; i < 4; i++) {
    int mi = m0 + tm + i;
    float* Crow = C + (long)mi*ldc + n0;
    #pragma unroll
    for (int j = 0; j < 4; j++) {
      int nj = tn + j;
      if (n0 + nj < N) {
        float v = acc[i][j] + bias[n0 + nj];
        if (RELU) v = fmaxf(v, 0.f);
        Crow[nj] = v;
      }
    }
  }
}

// ------------------------------------------------------------ assemble ----
__global__ void assemble_kernel(
    const float* __restrict__ enc_all, const float* __restrict__ zwhat_lt,
    const float* __restrict__ zwhere_lt, const float* __restrict__ hid_lt, int t,
    float* __restrict__ x_rel, float* __restrict__ x_tem, float* __restrict__ x_mt)
{
  long idx = (long)blockIdx.x * 256 + threadIdx.x;
  const int PER = 715;
  long item = idx / PER;
  int c = (int)(idx - item*PER);
  if (item >= NB) return;
  long ut = item*16 + t;
  if (c < 100)      x_rel[item*KREL + c]             = enc_all[ut*100 + c];
  else if (c < 103) x_rel[item*KREL + 100 + (c-100)] = zwhere_lt[ut*3 + (c-100)];
  else if (c < 153) x_rel[item*KREL + 106 + (c-103)] = zwhat_lt[ut*50 + (c-103)];
  else if (c < 409) x_rel[item*KREL + 206 + (c-153)] = hid_lt[ut*256 + (c-153)];
  else if (c < 665) x_tem[item*KTEM + 103 + (c-409)] = hid_lt[ut*256 + (c-409)];
  else              x_mt [item*KMT  + (c-665)]       = zwhat_lt[ut*50 + (c-665)];
}

// ----------------------------------------------------------- pointwise ----
// rel LSTM + m_where/s_where/z_where_i (serial chains, round-3 order)
// + FUSED per-item glimpse (bit-identical to the old gfill_kernel call:
// same expressions, reads the zw values this block just computed).
__global__ __launch_bounds__(256) void lstm_rel_kernel(
    const float* __restrict__ gates,
    float* __restrict__ h_rela, float* __restrict__ c_rela,
    float* __restrict__ x_rel, float* __restrict__ x_tem, float* __restrict__ x_mt,
    const float* __restrict__ zwhere_lt, const float* __restrict__ w_lwhere,
    const float* __restrict__ b_lwhere, const float* __restrict__ eps_where, int t,
    float* __restrict__ m_where, float* __restrict__ s_where,
    float* __restrict__ o_zwhere,
    const float* __restrict__ img, float* __restrict__ g_buf)
{
  __shared__ float sh[256];
  __shared__ float zwsh[3];
  long item = blockIdx.x;
  int j = threadIdx.x;
  const float* grow = gates + item*1024;
  float ig = grow[j], fg = grow[256+j], gg = grow[512+j], og = grow[768+j];
  long hi = item*256 + j;
  float c  = c_rela[hi];
  float c2 = sigm(fg)*c + sigm(ig)*tanhf(gg);
  float h2 = sigm(og)*tanhf(c2);
  c_rela[hi] = c2;
  h_rela[hi] = h2;
  sh[j] = h2;
  x_tem[item*KTEM + 359 + j] = h2;
  x_tem[item*KTEM + 615 + j] = h2;
  x_mt [item*KMT  +  50 + j] = h2;
  x_rel[item*KREL + 462 + j] = h2;   // for step t+1
  __syncthreads();
  if (j < 3) {
    long ut = item*16 + t;
    const float* wm  = w_lwhere + j*259;
    const float* wsr = w_lwhere + (j+3)*259;
    float am = b_lwhere[j], as = b_lwhere[j+3];
    #pragma unroll
    for (int k = 0; k < 3; k++) {
      float v = zwhere_lt[ut*3 + k];
      am = fmaf(v, wm[k], am);  as = fmaf(v, wsr[k], as);
    }
    for (int k = 0; k < 256; k++) {
      float v = sh[k];
      am = fmaf(v, wm[3+k], am);  as = fmaf(v, wsr[3+k], as);
    }
    float s = softp(as) + 1e-4f;
    float zw = am + s * eps_where[ut*3 + j];
    m_where[item*3 + j] = am;
    s_where[item*3 + j] = s;
    o_zwhere[ut*3 + j]  = zw;
    x_rel[item*KREL + 103 + j] = zw;   // zw_prev for step t+1
    zwsh[j] = zw;
  }
  __syncthreads();
  // fused glimpse: identical math to gfill_kernel (zstride path), item=unit
  {
    float gs = zwsh[0], gtx = zwsh[1], gty = zwsh[2];
    const float* im = img + item*2500;
    for (int p = j; p < 400; p += 256)
      g_buf[item*400 + p] = glimpse_px(im, gs, gtx, gty, p);
  }
}

__global__ void lstm_tem_kernel(const float* __restrict__ gates,
    const float* __restrict__ c_rela, float* __restrict__ o_htemp, int t,
    float* __restrict__ x_mt, float* __restrict__ x_tem,
    const float* __restrict__ o_zwhere)
{
  long idx = (long)blockIdx.x * 256 + threadIdx.x;
  if (idx >= (long)NB*256) return;
  long item = idx >> 8; int j = (int)(idx & 255);
  const float* grow = gates + item*1024;
  float ig = grow[j], fg = grow[256+j], gg = grow[512+j], og = grow[768+j];
  float c  = c_rela[idx];
  float c2 = sigm(fg)*c + sigm(ig)*tanhf(gg);
  float h2 = sigm(og)*tanhf(c2);
  long ut = item*16 + t;
  o_htemp[ut*256 + j] = h2;
  x_mt[item*KMT + 306 + j] = h2;
  if (j < 3) x_tem[item*KTEM + 100 + j] = o_zwhere[ut*3 + j];  // zw_prev for t+1
}

// pres + z_what sampling fused (z_what values identical to round-3 zwhat_kernel)
__global__ __launch_bounds__(256) void pres_kernel(
    const float* __restrict__ o_zwhere,
    const float* __restrict__ h_rela, const float* __restrict__ o_htemp,
    const float* __restrict__ w_lpres, const float* __restrict__ b_lpres,
    const float* __restrict__ zpres_lt, const float* __restrict__ u_pres, int t,
    const float* __restrict__ mt, const float* __restrict__ m_where,
    const float* __restrict__ s_where, const float* __restrict__ eps_what,
    float* __restrict__ o_zwhat, float* __restrict__ x_rel,
    float* __restrict__ o_zpres, float* __restrict__ out_klwhat,
    float* __restrict__ out_klwhere)
{
  int tid = threadIdx.x;
  long item = (long)blockIdx.x*4 + (tid >> 6);
  if (item >= NB) return;
  int l = tid & 63;
  long ut = item*16 + t;
  float part = 0.f;
  for (int c = l; c < 565; c += 64) {
    float x;
    if (c < 50) {
      float m = mt[item*100 + c];
      float s = softp(mt[item*100 + 50 + c]) + 1e-4f;
      x = m + s * eps_what[ut*50 + c];
      o_zwhat[ut*50 + c] = x;
      x_rel[item*KREL + 156 + c] = x;   // zwt_prev for step t+1
    }
    else if (c < 53)  x = o_zwhere[ut*3 + (c-50)];
    else if (c < 309) x = h_rela[item*256 + (c-53)];
    else              x = o_htemp[ut*256 + (c-309)];
    part = fmaf(x, w_lpres[c], part);
  }
  #pragma unroll
  for (int off = 32; off; off >>= 1) part += __shfl_down(part, off);
  float zpres = 0.f;
  if (l == 0) {
    float p = sigm(part + b_lpres[0]);
    zpres = (u_pres[ut] < p * zpres_lt[ut]) ? 1.f : 0.f;
    o_zpres[ut] = zpres;
  }
  float w = __shfl(zpres, 0);
  float kw = 0.f, kwh = 0.f;
  if (l < 50) {
    float m = mt[item*100 + l];
    float s = softp(mt[item*100 + 50 + l]) + 1e-4f;
    kw = -logf(s) + 0.5f*(s*s + m*m) - 0.5f;
  }
  if (l < 3) {
    float m = m_where[item*3 + l], s = s_where[item*3 + l];
    float m0 = (l == 0) ? 0.3f : 0.f;
    float s0 = (l == 0) ? 0.1f : 1.f;
    kwh = logf(s0 / s) + (s*s + (m-m0)*(m-m0)) / (2.f*s0*s0) - 0.5f;
  }
  #pragma unroll
  for (int off = 32; off; off >>= 1) {
    kw  += __shfl_down(kw,  off);
    kwh += __shfl_down(kwh, off);
  }
  if (l == 0) {
    out_klwhat[item]  += w * kw;
    out_klwhere[item] += w * kwh;
  }
}

// ---------------------------------------------------------------- host ----
extern "C" void kernel_launch(void* const* d_in, const int* in_sizes, int n_in,
                              void* d_out, int out_size, void* d_ws, size_t ws_size,
                              hipStream_t stream) {
  (void)in_sizes; (void)n_in; (void)out_size; (void)ws_size;
  const float* img       = (const float*)d_in[0];
  const float* zwhat_lt  = (const float*)d_in[1];
  const float* zwhere_lt = (const float*)d_in[2];
  const float* zpres_lt  = (const float*)d_in[3];
  const float* hid_lt    = (const float*)d_in[4];
  const float* eps_where = (const float*)d_in[5];
  const float* eps_what  = (const float*)d_in[6];
  const float* u_pres    = (const float*)d_in[7];
  const float* w_pro     = (const float*)d_in[8];
  const float* b_pro     = (const float*)d_in[9];
  const float* w_ge1     = (const float*)d_in[10];
  const float* b_ge1     = (const float*)d_in[11];
  const float* w_ge2     = (const float*)d_in[12];
  const float* b_ge2     = (const float*)d_in[13];
  const float* wih_rel   = (const float*)d_in[14];
  const float* whh_rel   = (const float*)d_in[15];
  const float* bih_rel   = (const float*)d_in[16];
  const float* bhh_rel   = (const float*)d_in[17];
  const float* wih_tem   = (const float*)d_in[18];
  const float* whh_tem   = (const float*)d_in[19];
  const float* bih_tem   = (const float*)d_in[20];
  const float* bhh_tem   = (const float*)d_in[21];
  const float* w_lwhere  = (const float*)d_in[22];
  const float* b_lwhere  = (const float*)d_in[23];
  const float* w_lwhat   = (const float*)d_in[24];
  const float* b_lwhat   = (const float*)d_in[25];
  const float* w_lpres   = (const float*)d_in[26];
  const float* b_lpres   = (const float*)d_in[27];

  float* ws = (float*)d_ws;
  float* W_relT   = ws;                       // 737280  (720 x 1024, k-major)
  float* W_temT   = W_relT + 737280;          // 901120  (880 x 1024, k-major)
  float* W_mt     = W_temT + 901120;          // 57600
  float* W_ge2p   = W_mt + 57600;             // 20800
  float* bias_rel = W_ge2p + 20800;           // 1024
  float* bias_tem = bias_rel + 1024;          // 1024
  float* zwb_all  = bias_tem + 1024;          // 196608
  float* enc_all  = zwb_all + 196608;         // 6553600
  float* g_buf    = enc_all + 6553600;        // 6553600 (CH*400)
  float* h1_buf   = g_buf + 6553600;          // 3407872 (CH*208)
  float* x_rel    = h1_buf + 3407872;         // 2949120
  float* x_tem    = x_rel + 2949120;          // 3604480
  float* x_mt     = x_tem + 3604480;          // 2359296
  float* gates    = x_mt + 2359296;           // 4194304
  float* h_rela   = gates + 4194304;          // 1048576
  float* c_rela   = h_rela + 1048576;         // 1048576
  float* m_where  = c_rela + 1048576;         // 12288
  float* s_where  = m_where + 12288;          // 12288
  float* mtbuf    = s_where + 12288;          // 409600

  float* out       = (float*)d_out;
  float* o_zwhat   = out + OUT_ZWHAT;
  float* o_zwhere  = out + OUT_ZWHERE;
  float* o_zpres   = out + OUT_ZPRES;
  float* o_klwhat  = out + OUT_KLWHAT;
  float* o_htemp   = out + OUT_HTEMP;

  // zero-init (was in prep_kernel; contiguous spans -> 3 memsets)
  // h1_buf..x_mt: 3407872+2949120+3604480+2359296 = 12320768 floats
  hipMemsetAsync(h1_buf, 0, 12320768L * sizeof(float), stream);
  // h_rela + c_rela: 2097152 floats
  hipMemsetAsync(h_rela, 0, 2097152L * sizeof(float), stream);
  // kl accumulators (output): 8192 floats
  hipMemsetAsync(o_klwhat, 0, 8192L * sizeof(float), stream);

  prep_kernel<<<6715, 256, 0, stream>>>(wih_rel, whh_rel, bih_rel, bhh_rel,
      wih_tem, whh_tem, bih_tem, bhh_tem, w_lwhat, w_ge2,
      W_relT, W_temT, W_mt, W_ge2p, bias_rel, bias_tem);

  zwb_kernel<<<4096, 256, 0, stream>>>(hid_lt, zwhere_lt, w_pro, b_pro, zwb_all);

  for (int c = 0; c < 4; c++) {
    gfill_kernel<<<CH/16, 256, 0, stream>>>(img, zwb_all + (long)c*CH*3, 3,
        (long)c*CH, 4, g_buf);
    gemmNK64_kernel<true><<<dim3(CH/64, 4), 256, 0, stream>>>(
        g_buf, 400, w_ge1, 400, b_ge1, h1_buf, KGE2, 400, 200);
    gemmNK64_kernel<false><<<dim3(CH/64, 2), 256, 0, stream>>>(
        h1_buf, KGE2, W_ge2p, KGE2, b_ge2, enc_all + (long)c*CH*100, 100, KGE2, 100);
  }

  for (int t = 0; t < TT; t++) {
    assemble_kernel<<<11440, 256, 0, stream>>>(enc_all, zwhat_lt, zwhere_lt,
        hid_lt, t, x_rel, x_tem, x_mt);
    gemmH_kernel<<<dim3(32, 16), 256, 0, stream>>>(x_rel, KREL, W_relT, NG,
        bias_rel, gates, NG, KREL);
    lstm_rel_kernel<<<4096, 256, 0, stream>>>(gates, h_rela, c_rela,
        x_rel, x_tem, x_mt, zwhere_lt, w_lwhere, b_lwhere, eps_where, t,
        m_where, s_where, o_zwhere, img, g_buf);
    gemmNK64_kernel<true><<<dim3(64, 4), 256, 0, stream>>>(
        g_buf, 400, w_ge1, 400, b_ge1, h1_buf, KGE2, 400, 200);
    gemmNK64_kernel<false><<<dim3(64, 2), 256, 0, stream>>>(
        h1_buf, KGE2, W_ge2p, KGE2, b_ge2, x_tem, KTEM, KGE2, 100);
    gemmH_kernel<<<dim3(32, 16), 256, 0, stream>>>(x_tem, KTEM, W_temT, NG,
        bias_tem, gates, NG, KTEM);
    lstm_tem_kernel<<<4096, 256, 0, stream>>>(gates, c_rela, o_htemp, t,
        x_mt, x_tem, o_zwhere);
    gemmNK64_kernel<false><<<dim3(64, 2), 256, 0, stream>>>(
        x_mt, KMT, W_mt, KMT, b_lwhat, mtbuf, 100, KMT, 100);
    pres_kernel<<<1024, 256, 0, stream>>>(o_zwhere, h_rela, o_htemp,
        w_lpres, b_lpres, zpres_lt, u_pres, t, mtbuf, m_where, s_where,
        eps_what, o_zwhat, x_rel, o_zpres, o_klwhat, o_klwhat + 4096);
  }
}

// Round 12
// 5225.020 us; speedup vs baseline: 5.4235x; 1.0483x over previous
//
#include <hip/hip_runtime.h>
#include <math.h>

#define DEV __device__ __forceinline__

// NUMERICS FREEZE: every output element keeps round-1's exact fp order:
// one thread per output, fmaf ascending over k, bias added once at the end.
// Only order-preserving optimizations (tiling/occupancy/fusion) allowed.
// Round-2 lesson: any reorder flips a u < p*zp threshold somewhere -> FAIL.
// GEMM exploration (rounds 6-11) converged: under the freeze,
// outputs/thread x waves = 4M/64 fixed; >=2 waves/SIMD needed (1/SIMD
// exposes latency: 112->160us) => <=32 out/thread => LDS >=1.5B/fma
// => ~105us/dispatch floor. gemmH (8x4 micro, 128x64 tile, A+B in LDS)
// measures 107us = floor+2%. Failed alternatives: 64-VGPR B buffer ->
// spill (898us); v_readlane B -> VALU tax (137us); s_load B -> L2 miss
// ~900cyc (129us); broadcast-B LDS -> same issue slots (117us).
// Round-12 lesson: launch-count reduction (fused gfill, memset prep) was
// NEUTRAL -> launch overhead is not the cost; kernel durations are.
// This round: t-loop small gemms were occupancy-starved (ge1 1 wg/CU,
// ge2/mt 0.5 wg/CU -> half the CUs idle). New gemmP: 64x32 tile, 4x2
// micro, double-buffered (1 barrier/tile) -> 2x CU coverage for ge2/mt.

constexpr int NB    = 4096;
constexpr int TT    = 16;
constexpr int KREL  = 720;   // [enc 100 | zwr 3 | zw_prev 3 | zwt_l 50 | zwt_prev 50 | hid 256 | h 256 | pad 2]
constexpr int KTEM  = 880;   // [enc 100 | zw_prev 3 | hid 256 | h 256 | h(whh) 256 | pad 9]
constexpr int KMT   = 576;   // [zwt_l 50 | h_rela 256 | h_temp 256 | pad 14]
constexpr int KGE2  = 208;   // 200 padded
constexpr int NG    = 1024;
constexpr int CH    = 16384; // enc chunk units

constexpr long OUT_ZWHAT   = 0L;
constexpr long OUT_ZWHERE  = 3276800L;
constexpr long OUT_ZPRES   = 3473408L;
constexpr long OUT_KLWHAT  = 3538944L;
constexpr long OUT_HTEMP   = 3547136L;

DEV float sigm(float x)  { return 1.f / (1.f + expf(-x)); }
DEV float softp(float x) { return fmaxf(x, 0.f) + log1pf(expf(-fabsf(x))); }

// ---------------------------------------------------------------- prep ----
// W_relT/W_temT are k-major (transposed): W*T[k][n], n contiguous.
// Zero-init segments moved to hipMemsetAsync in kernel_launch.
__global__ void prep_kernel(
    const float* __restrict__ wih_rel, const float* __restrict__ whh_rel,
    const float* __restrict__ bih_rel, const float* __restrict__ bhh_rel,
    const float* __restrict__ wih_tem, const float* __restrict__ whh_tem,
    const float* __restrict__ bih_tem, const float* __restrict__ bhh_tem,
    const float* __restrict__ w_lwhat, const float* __restrict__ w_ge2,
    float* __restrict__ W_relT, float* __restrict__ W_temT, float* __restrict__ W_mt,
    float* __restrict__ W_ge2p,
    float* __restrict__ bias_rel, float* __restrict__ bias_tem)
{
  long idx = (long)blockIdx.x * 256 + threadIdx.x;
  if (idx < 737280) { int k = (int)(idx >> 10), j = (int)(idx & 1023);
    W_relT[idx] = (k < 462) ? wih_rel[j*462+k] : (k < 718 ? whh_rel[j*256 + (k-462)] : 0.f); return; }
  idx -= 737280;
  if (idx < 901120) { int k = (int)(idx >> 10), j = (int)(idx & 1023);
    W_temT[idx] = (k < 615) ? wih_tem[j*615+k] : (k < 871 ? whh_tem[j*256 + (k-615)] : 0.f); return; }
  idx -= 901120;
  if (idx < 57600) { int j = (int)(idx/576), k = (int)(idx - (long)j*576);
    W_mt[idx] = (k < 562) ? w_lwhat[j*562+k] : 0.f; return; }
  idx -= 57600;
  if (idx < 20800) { int j = (int)(idx/208), k = (int)(idx - (long)j*208);
    W_ge2p[idx] = (k < 200) ? w_ge2[j*200+k] : 0.f; return; }
  idx -= 20800;
  if (idx < 1024) { bias_rel[idx] = bih_rel[idx] + bhh_rel[idx]; return; }
  idx -= 1024;
  if (idx < 1024) { bias_tem[idx] = bih_tem[idx] + bhh_tem[idx]; return; }
}

// z_where_bias for all 65536 units (round-1 reduction order)
__global__ __launch_bounds__(256) void zwb_kernel(
    const float* __restrict__ hid_all, const float* __restrict__ zwr_all,
    const float* __restrict__ w_pro, const float* __restrict__ b_pro,
    float* __restrict__ zwb_all)
{
  int tid = threadIdx.x;
  long unit0 = (long)blockIdx.x * 16;
  int u = tid >> 4, l = tid & 15;
  const float* hid = hid_all + (unit0 + u) * 256;
  float p0 = 0.f, p1 = 0.f, p2 = 0.f;
  for (int k = l; k < 256; k += 16) {
    float h = hid[k];
    p0 = fmaf(h, w_pro[k],       p0);
    p1 = fmaf(h, w_pro[256 + k], p1);
    p2 = fmaf(h, w_pro[512 + k], p2);
  }
  #pragma unroll
  for (int off = 8; off; off >>= 1) {
    p0 += __shfl_down(p0, off, 16);
    p1 += __shfl_down(p1, off, 16);
    p2 += __shfl_down(p2, off, 16);
  }
  if (l == 0) {
    long unit = unit0 + u;
    zwb_all[unit*3+0] = fmaxf(p0 + b_pro[0], 0.f) + zwr_all[unit*3+0];
    zwb_all[unit*3+1] = fmaxf(p1 + b_pro[1], 0.f) + zwr_all[unit*3+1];
    zwb_all[unit*3+2] = fmaxf(p2 + b_pro[2], 0.f) + zwr_all[unit*3+2];
  }
}

// ------------------------------------------------------------- glimpse ----
DEV float bilin_sample(const float* im, int y, int x) {
  bool valid = ((unsigned)x < 50u) && ((unsigned)y < 50u);
  int yc = min(max(y, 0), 49), xc = min(max(x, 0), 49);
  float v = im[yc*50 + xc];
  return valid ? v : 0.f;
}

DEV float glimpse_px(const float* im, float s, float tx, float ty, int pix) {
  int iyi = pix / 20, ixi = pix - iyi*20;
  float bx = (2.f*ixi + 1.f)/20.f - 1.f;
  float by = (2.f*iyi + 1.f)/20.f - 1.f;
  float x = s*bx + tx, y = s*by + ty;
  float ix = ((x + 1.f)*50.f - 1.f)*0.5f;
  float iy = ((y + 1.f)*50.f - 1.f)*0.5f;
  float x0f = floorf(ix), y0f = floorf(iy);
  float wx = ix - x0f, wy = iy - y0f;
  int x0 = (int)x0f, y0 = (int)y0f;
  float v00 = bilin_sample(im, y0,   x0  );
  float v01 = bilin_sample(im, y0,   x0+1);
  float v10 = bilin_sample(im, y0+1, x0  );
  float v11 = bilin_sample(im, y0+1, x0+1);
  return v00*(1.f-wx)*(1.f-wy) + v01*wx*(1.f-wy)
       + v10*(1.f-wx)*wy       + v11*wx*wy;
}

__global__ __launch_bounds__(256) void gfill_kernel(
    const float* __restrict__ img, const float* __restrict__ zwbp, int zstride,
    long ibase, int shift, float* __restrict__ g_out)
{
  __shared__ float zwb[16][3];
  int tid = threadIdx.x;
  long unit0 = (long)blockIdx.x * 16;
  if (tid < 48) {
    int u = tid / 3, j = tid - u*3;
    zwb[u][j] = zwbp[(unit0 + u)*(long)zstride + j];
  }
  __syncthreads();
  for (int p = tid; p < 16*400; p += 256) {
    int u = p / 400, pix = p - u*400;
    long item = (ibase + unit0 + u) >> shift;
    const float* im = img + item*2500;
    g_out[(unit0+u)*400 + pix] =
        glimpse_px(im, zwb[u][0], zwb[u][1], zwb[u][2], pix);
  }
}

// --------------------------------------------------------------- GEMMs ----
// Big-gate GEMM "gemmH" (round-3 verified, 107us): 128x64 tile, 256 threads,
// 8x4 micro, double-buffered LDS, 2 wgs/CU = 2 waves/SIMD. This sits at the
// order-preserving structural floor (see header comment).
// Per-output order unchanged: fmaf ascending k, bias last (bit-identical).
// Thread owns rows {tm+0..3, tm+64..67} x cols {tn+0..3}.
__global__ __launch_bounds__(256, 2) void gemmH_kernel(
    const float* __restrict__ A, int lda,
    const float* __restrict__ Wt, int ldwt,
    const float* __restrict__ bias,
    float* __restrict__ C, int ldc, int K)
{
  __shared__ float As[2][16][132];
  __shared__ float Bs[2][16][68];
  int tid = threadIdx.x;
  int m0 = blockIdx.x << 7, n0 = blockIdx.y << 6;
  // A staging: thread -> row m0+ar, k-cols ak..ak+7 (2-way write alias, free)
  int ar = tid >> 1, ak = (tid & 1) << 3;
  const float* Ap = A + (long)(m0 + ar)*lda + ak;
  // B staging: thread -> k-row bk, n-cols bn..bn+3
  int bk = tid >> 4, bn = (tid & 15) << 2;
  const float* Bp = Wt + (long)bk*ldwt + n0 + bn;
  // compute fragment offsets
  int tm = (tid & 15) << 2;          // 0,4,...,60  (row group; +0 / +64)
  int tn = ((tid >> 4) & 15) << 2;   // 0,4,...,60  (col group)
  float acc[8][4] = {};
  float4 a0 = *(const float4*)(Ap);
  float4 a1 = *(const float4*)(Ap + 4);
  float4 b0 = *(const float4*)(Bp);
  As[0][ak+0][ar] = a0.x; As[0][ak+1][ar] = a0.y;
  As[0][ak+2][ar] = a0.z; As[0][ak+3][ar] = a0.w;
  As[0][ak+4][ar] = a1.x; As[0][ak+5][ar] = a1.y;
  As[0][ak+6][ar] = a1.z; As[0][ak+7][ar] = a1.w;
  *(float4*)&Bs[0][bk][bn] = b0;
  __syncthreads();
  int buf = 0;
  for (int k0 = 16;; k0 += 16) {
    bool more = k0 < K;
    if (more) {
      a0 = *(const float4*)(Ap + k0);
      a1 = *(const float4*)(Ap + k0 + 4);
      b0 = *(const float4*)(Bp + (long)k0*ldwt);
    }
    #pragma unroll
    for (int k = 0; k < 16; k++) {
      float4 av0 = *(const float4*)&As[buf][k][tm];
      float4 av1 = *(const float4*)&As[buf][k][tm+64];
      float4 bv  = *(const float4*)&Bs[buf][k][tn];
      float a[8] = {av0.x,av0.y,av0.z,av0.w,av1.x,av1.y,av1.z,av1.w};
      float b[4] = {bv.x,bv.y,bv.z,bv.w};
      #pragma unroll
      for (int i = 0; i < 8; i++)
        #pragma unroll
        for (int j = 0; j < 4; j++)
          acc[i][j] = fmaf(a[i], b[j], acc[i][j]);
    }
    if (!more) break;
    buf ^= 1;
    As[buf][ak+0][ar] = a0.x; As[buf][ak+1][ar] = a0.y;
    As[buf][ak+2][ar] = a0.z; As[buf][ak+3][ar] = a0.w;
    As[buf][ak+4][ar] = a1.x; As[buf][ak+5][ar] = a1.y;
    As[buf][ak+6][ar] = a1.z; As[buf][ak+7][ar] = a1.w;
    *(float4*)&Bs[buf][bk][bn] = b0;
    __syncthreads();
  }
  float bj[4];
  #pragma unroll
  for (int j = 0; j < 4; j++) bj[j] = bias[n0 + tn + j];
  #pragma unroll
  for (int i = 0; i < 8; i++) {
    int mi = m0 + tm + (i & 3) + ((i >> 2) << 6);
    float* Crow = C + (long)mi*ldc + n0;
    float4 v = make_float4(acc[i][0]+bj[0], acc[i][1]+bj[1],
                           acc[i][2]+bj[2], acc[i][3]+bj[3]);
    *(float4*)(Crow + tn) = v;
  }
}

// 64x64 tile, 4x4 micro, N-bounded, optional ReLU. K % 16 == 0 REQUIRED.
// Used in the enc phase (grid large enough there: 4 wgs/CU).
template<bool RELU>
__global__ __launch_bounds__(256) void gemmNK64_kernel(
    const float* __restrict__ A, int lda,
    const float* __restrict__ W, int ldw,
    const float* __restrict__ bias,
    float* __restrict__ C, int ldc, int K, int N)
{
  __shared__ float As[16][68];
  __shared__ float Bs[16][68];
  int tid = threadIdx.x;
  int m0 = blockIdx.x << 6, n0 = blockIdx.y << 6;
  int r  = tid >> 2;
  int kq = (tid & 3) << 2;
  const float* Ap = A + (long)(m0 + r)*lda + kq;
  const float* Wp = W + (long)(n0 + r)*ldw + kq;
  bool wv = (n0 + r) < N;
  int tm = (tid & 15) << 2;
  int tn = ((tid >> 4) & 15) << 2;
  float acc[4][4] = {};
  float4 a0 = *(const float4*)Ap;
  float4 b0 = wv ? *(const float4*)Wp : make_float4(0.f,0.f,0.f,0.f);
  for (int k0 = 16;; k0 += 16) {
    __syncthreads();
    As[kq+0][r]=a0.x; As[kq+1][r]=a0.y; As[kq+2][r]=a0.z; As[kq+3][r]=a0.w;
    Bs[kq+0][r]=b0.x; Bs[kq+1][r]=b0.y; Bs[kq+2][r]=b0.z; Bs[kq+3][r]=b0.w;
    __syncthreads();
    if (k0 < K) {
      a0 = *(const float4*)(Ap + k0);
      b0 = wv ? *(const float4*)(Wp + k0) : make_float4(0.f,0.f,0.f,0.f);
    }
    #pragma unroll
    for (int k = 0; k < 16; k++) {
      float4 av = *(const float4*)&As[k][tm];
      float4 bv = *(const float4*)&Bs[k][tn];
      float a[4] = {av.x,av.y,av.z,av.w};
      float b[4] = {bv.x,bv.y,bv.z,bv.w};
      #pragma unroll
      for (int i = 0; i < 4; i++)
        #pragma unroll
        for (int j = 0; j < 4; j++)
          acc[i][j] = fmaf(a[i], b[j], acc[i][j]);
    }
    if (k0 >= K) break;
  }
  #pragma unroll
  for (int i = 0; i < 4; i++) {
    int mi = m0 + tm + i;
    float* Crow = C + (long)mi*ldc + n0;
    #pragma unroll
    for (int j = 0; j < 4; j++) {
      int nj = tn + j;
      if (n0 + nj < N) {
        float v = acc[i][j] + bias[n0 + nj];
        if (RELU) v = fmaxf(v, 0.f);
        Crow[nj] = v;
      }
    }
  }
}

// 64x32 tile, 4x2 micro, double-buffered (1 barrier/tile), N-bounded,
// optional ReLU. K % 16 == 0 REQUIRED. For the t-loop small gemms where
// the 64x64 kernel's grid left half the CUs idle (ge2/mt were 0.5 wg/CU).
// Per-output order: one thread per output, fmaf ascending k, bias last
// (bit-identical to gemmNK64's outputs).
template<bool RELU>
__global__ __launch_bounds__(256, 2) void gemmP_kernel(
    const float* __restrict__ A, int lda,
    const float* __restrict__ W, int ldw,
    const float* __restrict__ bias,
    float* __restrict__ C, int ldc, int K, int N)
{
  __shared__ float As[2][16][68];
  __shared__ float Bs[2][16][36];
  int tid = threadIdx.x;
  int m0 = blockIdx.x << 6, n0 = blockIdx.y << 5;
  // A staging: thread -> row m0+ar, k-cols akq..akq+3
  int ar = tid >> 2, akq = (tid & 3) << 2;
  const float* Ap = A + (long)(m0 + ar)*lda + akq;
  // B staging: thread -> col n0+br, k-rows bkq, bkq+1
  int br = tid & 31, bkq = (tid >> 5) << 1;
  const float* Wp = W + (long)(n0 + br)*ldw + bkq;
  bool wv = (n0 + br) < N;
  int tm = (tid & 15) << 2;   // 0,4,...,60
  int tn = (tid >> 4) << 1;   // 0,2,...,30
  float acc[4][2] = {};
  float4 a0 = *(const float4*)Ap;
  float2 b0 = wv ? *(const float2*)Wp : make_float2(0.f, 0.f);
  As[0][akq+0][ar]=a0.x; As[0][akq+1][ar]=a0.y;
  As[0][akq+2][ar]=a0.z; As[0][akq+3][ar]=a0.w;
  Bs[0][bkq+0][br]=b0.x; Bs[0][bkq+1][br]=b0.y;
  __syncthreads();
  int buf = 0;
  for (int k0 = 16;; k0 += 16) {
    bool more = k0 < K;
    if (more) {
      a0 = *(const float4*)(Ap + k0);
      b0 = wv ? *(const float2*)(Wp + k0) : make_float2(0.f, 0.f);
    }
    #pragma unroll
    for (int k = 0; k < 16; k++) {
      float4 av = *(const float4*)&As[buf][k][tm];
      float2 bv = *(const float2*)&Bs[buf][k][tn];
      float a[4] = {av.x,av.y,av.z,av.w};
      float b[2] = {bv.x,bv.y};
      #pragma unroll
      for (int i = 0; i < 4; i++)
        #pragma unroll
        for (int j = 0; j < 2; j++)
          acc[i][j] = fmaf(a[i], b[j], acc[i][j]);
    }
    if (!more) break;
    buf ^= 1;
    As[buf][akq+0][ar]=a0.x; As[buf][akq+1][ar]=a0.y;
    As[buf][akq+2][ar]=a0.z; As[buf][akq+3][ar]=a0.w;
    Bs[buf][bkq+0][br]=b0.x; Bs[buf][bkq+1][br]=b0.y;
    __syncthreads();
  }
  #pragma unroll
  for (int i = 0; i < 4; i++) {
    int mi = m0 + tm + i;
    float* Crow = C + (long)mi*ldc + n0;
    #pragma unroll
    for (int j = 0; j < 2; j++) {
      int nj = tn + j;
      if (n0 + nj < N) {
        float v = acc[i][j] + bias[n0 + nj];
        if (RELU) v = fmaxf(v, 0.f);
        Crow[nj] = v;
      }
    }
  }
}

// ------------------------------------------------------------ assemble ----
__global__ void assemble_kernel(
    const float* __restrict__ enc_all, const float* __restrict__ zwhat_lt,
    const float* __restrict__ zwhere_lt, const float* __restrict__ hid_lt, int t,
    float* __restrict__ x_rel, float* __restrict__ x_tem, float* __restrict__ x_mt)
{
  long idx = (long)blockIdx.x * 256 + threadIdx.x;
  const int PER = 715;
  long item = idx / PER;
  int c = (int)(idx - item*PER);
  if (item >= NB) return;
  long ut = item*16 + t;
  if (c < 100)      x_rel[item*KREL + c]             = enc_all[ut*100 + c];
  else if (c < 103) x_rel[item*KREL + 100 + (c-100)] = zwhere_lt[ut*3 + (c-100)];
  else if (c < 153) x_rel[item*KREL + 106 + (c-103)] = zwhat_lt[ut*50 + (c-103)];
  else if (c < 409) x_rel[item*KREL + 206 + (c-153)] = hid_lt[ut*256 + (c-153)];
  else if (c < 665) x_tem[item*KTEM + 103 + (c-409)] = hid_lt[ut*256 + (c-409)];
  else              x_mt [item*KMT  + (c-665)]       = zwhat_lt[ut*50 + (c-665)];
}

// ----------------------------------------------------------- pointwise ----
// rel LSTM + m_where/s_where/z_where_i (serial chains, round-3 order)
// + FUSED per-item glimpse (bit-identical to the old gfill_kernel call:
// same expressions, reads the zw values this block just computed).
__global__ __launch_bounds__(256) void lstm_rel_kernel(
    const float* __restrict__ gates,
    float* __restrict__ h_rela, float* __restrict__ c_rela,
    float* __restrict__ x_rel, float* __restrict__ x_tem, float* __restrict__ x_mt,
    const float* __restrict__ zwhere_lt, const float* __restrict__ w_lwhere,
    const float* __restrict__ b_lwhere, const float* __restrict__ eps_where, int t,
    float* __restrict__ m_where, float* __restrict__ s_where,
    float* __restrict__ o_zwhere,
    const float* __restrict__ img, float* __restrict__ g_buf)
{
  __shared__ float sh[256];
  __shared__ float zwsh[3];
  long item = blockIdx.x;
  int j = threadIdx.x;
  const float* grow = gates + item*1024;
  float ig = grow[j], fg = grow[256+j], gg = grow[512+j], og = grow[768+j];
  long hi = item*256 + j;
  float c  = c_rela[hi];
  float c2 = sigm(fg)*c + sigm(ig)*tanhf(gg);
  float h2 = sigm(og)*tanhf(c2);
  c_rela[hi] = c2;
  h_rela[hi] = h2;
  sh[j] = h2;
  x_tem[item*KTEM + 359 + j] = h2;
  x_tem[item*KTEM + 615 + j] = h2;
  x_mt [item*KMT  +  50 + j] = h2;
  x_rel[item*KREL + 462 + j] = h2;   // for step t+1
  __syncthreads();
  if (j < 3) {
    long ut = item*16 + t;
    const float* wm  = w_lwhere + j*259;
    const float* wsr = w_lwhere + (j+3)*259;
    float am = b_lwhere[j], as = b_lwhere[j+3];
    #pragma unroll
    for (int k = 0; k < 3; k++) {
      float v = zwhere_lt[ut*3 + k];
      am = fmaf(v, wm[k], am);  as = fmaf(v, wsr[k], as);
    }
    for (int k = 0; k < 256; k++) {
      float v = sh[k];
      am = fmaf(v, wm[3+k], am);  as = fmaf(v, wsr[3+k], as);
    }
    float s = softp(as) + 1e-4f;
    float zw = am + s * eps_where[ut*3 + j];
    m_where[item*3 + j] = am;
    s_where[item*3 + j] = s;
    o_zwhere[ut*3 + j]  = zw;
    x_rel[item*KREL + 103 + j] = zw;   // zw_prev for step t+1
    zwsh[j] = zw;
  }
  __syncthreads();
  // fused glimpse: identical math to gfill_kernel (zstride path), item=unit
  {
    float gs = zwsh[0], gtx = zwsh[1], gty = zwsh[2];
    const float* im = img + item*2500;
    for (int p = j; p < 400; p += 256)
      g_buf[item*400 + p] = glimpse_px(im, gs, gtx, gty, p);
  }
}

__global__ void lstm_tem_kernel(const float* __restrict__ gates,
    const float* __restrict__ c_rela, float* __restrict__ o_htemp, int t,
    float* __restrict__ x_mt, float* __restrict__ x_tem,
    const float* __restrict__ o_zwhere)
{
  long idx = (long)blockIdx.x * 256 + threadIdx.x;
  if (idx >= (long)NB*256) return;
  long item = idx >> 8; int j = (int)(idx & 255);
  const float* grow = gates + item*1024;
  float ig = grow[j], fg = grow[256+j], gg = grow[512+j], og = grow[768+j];
  float c  = c_rela[idx];
  float c2 = sigm(fg)*c + sigm(ig)*tanhf(gg);
  float h2 = sigm(og)*tanhf(c2);
  long ut = item*16 + t;
  o_htemp[ut*256 + j] = h2;
  x_mt[item*KMT + 306 + j] = h2;
  if (j < 3) x_tem[item*KTEM + 100 + j] = o_zwhere[ut*3 + j];  // zw_prev for t+1
}

// pres + z_what sampling fused (z_what values identical to round-3 zwhat_kernel)
__global__ __launch_bounds__(256) void pres_kernel(
    const float* __restrict__ o_zwhere,
    const float* __restrict__ h_rela, const float* __restrict__ o_htemp,
    const float* __restrict__ w_lpres, const float* __restrict__ b_lpres,
    const float* __restrict__ zpres_lt, const float* __restrict__ u_pres, int t,
    const float* __restrict__ mt, const float* __restrict__ m_where,
    const float* __restrict__ s_where, const float* __restrict__ eps_what,
    float* __restrict__ o_zwhat, float* __restrict__ x_rel,
    float* __restrict__ o_zpres, float* __restrict__ out_klwhat,
    float* __restrict__ out_klwhere)
{
  int tid = threadIdx.x;
  long item = (long)blockIdx.x*4 + (tid >> 6);
  if (item >= NB) return;
  int l = tid & 63;
  long ut = item*16 + t;
  float part = 0.f;
  for (int c = l; c < 565; c += 64) {
    float x;
    if (c < 50) {
      float m = mt[item*100 + c];
      float s = softp(mt[item*100 + 50 + c]) + 1e-4f;
      x = m + s * eps_what[ut*50 + c];
      o_zwhat[ut*50 + c] = x;
      x_rel[item*KREL + 156 + c] = x;   // zwt_prev for step t+1
    }
    else if (c < 53)  x = o_zwhere[ut*3 + (c-50)];
    else if (c < 309) x = h_rela[item*256 + (c-53)];
    else              x = o_htemp[ut*256 + (c-309)];
    part = fmaf(x, w_lpres[c], part);
  }
  #pragma unroll
  for (int off = 32; off; off >>= 1) part += __shfl_down(part, off);
  float zpres = 0.f;
  if (l == 0) {
    float p = sigm(part + b_lpres[0]);
    zpres = (u_pres[ut] < p * zpres_lt[ut]) ? 1.f : 0.f;
    o_zpres[ut] = zpres;
  }
  float w = __shfl(zpres, 0);
  float kw = 0.f, kwh = 0.f;
  if (l < 50) {
    float m = mt[item*100 + l];
    float s = softp(mt[item*100 + 50 + l]) + 1e-4f;
    kw = -logf(s) + 0.5f*(s*s + m*m) - 0.5f;
  }
  if (l < 3) {
    float m = m_where[item*3 + l], s = s_where[item*3 + l];
    float m0 = (l == 0) ? 0.3f : 0.f;
    float s0 = (l == 0) ? 0.1f : 1.f;
    kwh = logf(s0 / s) + (s*s + (m-m0)*(m-m0)) / (2.f*s0*s0) - 0.5f;
  }
  #pragma unroll
  for (int off = 32; off; off >>= 1) {
    kw  += __shfl_down(kw,  off);
    kwh += __shfl_down(kwh, off);
  }
  if (l == 0) {
    out_klwhat[item]  += w * kw;
    out_klwhere[item] += w * kwh;
  }
}

// ---------------------------------------------------------------- host ----
extern "C" void kernel_launch(void* const* d_in, const int* in_sizes, int n_in,
                              void* d_out, int out_size, void* d_ws, size_t ws_size,
                              hipStream_t stream) {
  (void)in_sizes; (void)n_in; (void)out_size; (void)ws_size;
  const float* img       = (const float*)d_in[0];
  const float* zwhat_lt  = (const float*)d_in[1];
  const float* zwhere_lt = (const float*)d_in[2];
  const float* zpres_lt  = (const float*)d_in[3];
  const float* hid_lt    = (const float*)d_in[4];
  const float* eps_where = (const float*)d_in[5];
  const float* eps_what  = (const float*)d_in[6];
  const float* u_pres    = (const float*)d_in[7];
  const float* w_pro     = (const float*)d_in[8];
  const float* b_pro     = (const float*)d_in[9];
  const float* w_ge1     = (const float*)d_in[10];
  const float* b_ge1     = (const float*)d_in[11];
  const float* w_ge2     = (const float*)d_in[12];
  const float* b_ge2     = (const float*)d_in[13];
  const float* wih_rel   = (const float*)d_in[14];
  const float* whh_rel   = (const float*)d_in[15];
  const float* bih_rel   = (const float*)d_in[16];
  const float* bhh_rel   = (const float*)d_in[17];
  const float* wih_tem   = (const float*)d_in[18];
  const float* whh_tem   = (const float*)d_in[19];
  const float* bih_tem   = (const float*)d_in[20];
  const float* bhh_tem   = (const float*)d_in[21];
  const float* w_lwhere  = (const float*)d_in[22];
  const float* b_lwhere  = (const float*)d_in[23];
  const float* w_lwhat   = (const float*)d_in[24];
  const float* b_lwhat   = (const float*)d_in[25];
  const float* w_lpres   = (const float*)d_in[26];
  const float* b_lpres   = (const float*)d_in[27];

  float* ws = (float*)d_ws;
  float* W_relT   = ws;                       // 737280  (720 x 1024, k-major)
  float* W_temT   = W_relT + 737280;          // 901120  (880 x 1024, k-major)
  float* W_mt     = W_temT + 901120;          // 57600
  float* W_ge2p   = W_mt + 57600;             // 20800
  float* bias_rel = W_ge2p + 20800;           // 1024
  float* bias_tem = bias_rel + 1024;          // 1024
  float* zwb_all  = bias_tem + 1024;          // 196608
  float* enc_all  = zwb_all + 196608;         // 6553600
  float* g_buf    = enc_all + 6553600;        // 6553600 (CH*400)
  float* h1_buf   = g_buf + 6553600;          // 3407872 (CH*208)
  float* x_rel    = h1_buf + 3407872;         // 2949120
  float* x_tem    = x_rel + 2949120;          // 3604480
  float* x_mt     = x_tem + 3604480;          // 2359296
  float* gates    = x_mt + 2359296;           // 4194304
  float* h_rela   = gates + 4194304;          // 1048576
  float* c_rela   = h_rela + 1048576;         // 1048576
  float* m_where  = c_rela + 1048576;         // 12288
  float* s_where  = m_where + 12288;          // 12288
  float* mtbuf    = s_where + 12288;          // 409600

  float* out       = (float*)d_out;
  float* o_zwhat   = out + OUT_ZWHAT;
  float* o_zwhere  = out + OUT_ZWHERE;
  float* o_zpres   = out + OUT_ZPRES;
  float* o_klwhat  = out + OUT_KLWHAT;
  float* o_htemp   = out + OUT_HTEMP;

  // zero-init (contiguous spans -> 3 memsets)
  // h1_buf..x_mt: 3407872+2949120+3604480+2359296 = 12320768 floats
  hipMemsetAsync(h1_buf, 0, 12320768L * sizeof(float), stream);
  // h_rela + c_rela: 2097152 floats
  hipMemsetAsync(h_rela, 0, 2097152L * sizeof(float), stream);
  // kl accumulators (output): 8192 floats
  hipMemsetAsync(o_klwhat, 0, 8192L * sizeof(float), stream);

  prep_kernel<<<6715, 256, 0, stream>>>(wih_rel, whh_rel, bih_rel, bhh_rel,
      wih_tem, whh_tem, bih_tem, bhh_tem, w_lwhat, w_ge2,
      W_relT, W_temT, W_mt, W_ge2p, bias_rel, bias_tem);

  zwb_kernel<<<4096, 256, 0, stream>>>(hid_lt, zwhere_lt, w_pro, b_pro, zwb_all);

  for (int c = 0; c < 4; c++) {
    gfill_kernel<<<CH/16, 256, 0, stream>>>(img, zwb_all + (long)c*CH*3, 3,
        (long)c*CH, 4, g_buf);
    gemmNK64_kernel<true><<<dim3(CH/64, 4), 256, 0, stream>>>(
        g_buf, 400, w_ge1, 400, b_ge1, h1_buf, KGE2, 400, 200);
    gemmNK64_kernel<false><<<dim3(CH/64, 2), 256, 0, stream>>>(
        h1_buf, KGE2, W_ge2p, KGE2, b_ge2, enc_all + (long)c*CH*100, 100, KGE2, 100);
  }

  for (int t = 0; t < TT; t++) {
    assemble_kernel<<<11440, 256, 0, stream>>>(enc_all, zwhat_lt, zwhere_lt,
        hid_lt, t, x_rel, x_tem, x_mt);
    gemmH_kernel<<<dim3(32, 16), 256, 0, stream>>>(x_rel, KREL, W_relT, NG,
        bias_rel, gates, NG, KREL);
    lstm_rel_kernel<<<4096, 256, 0, stream>>>(gates, h_rela, c_rela,
        x_rel, x_tem, x_mt, zwhere_lt, w_lwhere, b_lwhere, eps_where, t,
        m_where, s_where, o_zwhere, img, g_buf);
    gemmP_kernel<true><<<dim3(64, 7), 256, 0, stream>>>(
        g_buf, 400, w_ge1, 400, b_ge1, h1_buf, KGE2, 400, 200);
    gemmP_kernel<false><<<dim3(64, 4), 256, 0, stream>>>(
        h1_buf, KGE2, W_ge2p, KGE2, b_ge2, x_tem, KTEM, KGE2, 100);
    gemmH_kernel<<<dim3(32, 16), 256, 0, stream>>>(x_tem, KTEM, W_temT, NG,
        bias_tem, gates, NG, KTEM);
    lstm_tem_kernel<<<4096, 256, 0, stream>>>(gates, c_rela, o_htemp, t,
        x_mt, x_tem, o_zwhere);
    gemmP_kernel<false><<<dim3(64, 4), 256, 0, stream>>>(
        x_mt, KMT, W_mt, KMT, b_lwhat, mtbuf, 100, KMT, 100);
    pres_kernel<<<1024, 256, 0, stream>>>(o_zwhere, h_rela, o_htemp,
        w_lpres, b_lpres, zpres_lt, u_pres, t, mtbuf, m_where, s_where,
        eps_what, o_zwhat, x_rel, o_zpres, o_klwhat, o_klwhat + 4096);
  }
}